// Round 2
// baseline (12576.790 us; speedup 1.0000x reference)
//
#include <hip/hip_runtime.h>
#include <hip/hip_bf16.h>
#include <cstdint>
#include <cstddef>

// ---------------- types ----------------
typedef float  f32x4  __attribute__((ext_vector_type(4)));
typedef __bf16 bf16x8 __attribute__((ext_vector_type(8)));

// ---------------- dims ----------------
#define BATCH      256
#define SEQT       32
#define INPUT_SIZE 1024
#define MEM_SLOTS  8
#define MEM_SIZE   1024
#define S1         9
#define TOTAL_QKV  3072
#define NUM_GATES  2048

__device__ __forceinline__ void split3(float a, __bf16& h, __bf16& m, __bf16& l) {
    h = (__bf16)a; float r  = a - (float)h;   // exact (Sterbenz)
    m = (__bf16)r; float r2 = r - (float)m;   // exact
    l = (__bf16)r2;
}

// =====================================================================
// Weight transpose + 3-way bf16 split: W (K x N) -> H/M/L (N x K) bf16
// grid(K/32, N/32), block(32,8)
// =====================================================================
__global__ void k_transpose_split3(const float* __restrict__ W,
                                   __bf16* __restrict__ H, __bf16* __restrict__ M,
                                   __bf16* __restrict__ L, int N, int K) {
    __shared__ float tile[32][33];
    int k0 = blockIdx.x * 32, n0 = blockIdx.y * 32;
    int tx = threadIdx.x, ty = threadIdx.y;
    #pragma unroll
    for (int i = ty; i < 32; i += 8)
        tile[i][tx] = W[(size_t)(k0 + i) * N + (n0 + tx)];
    __syncthreads();
    #pragma unroll
    for (int i = ty; i < 32; i += 8) {
        float a = tile[tx][i];
        __bf16 h, m, l; split3(a, h, m, l);
        size_t idx = (size_t)(n0 + i) * K + (k0 + tx);
        H[idx] = h; M[idx] = m; L[idx] = l;
    }
}

// =====================================================================
// vec4 copy
// =====================================================================
__global__ void k_copy(const float* __restrict__ src, float* __restrict__ dst, int n4) {
    int i = blockIdx.x * 256 + threadIdx.x;
    if (i < n4) ((f32x4*)dst)[i] = ((const f32x4*)src)[i];
}

// =====================================================================
// tanh elementwise (vec4)
// =====================================================================
__global__ void k_tanh(const float* __restrict__ src, float* __restrict__ dst, int n4) {
    int i = blockIdx.x * 256 + threadIdx.x;
    if (i >= n4) return;
    f32x4 v = ((const f32x4*)src)[i];
    #pragma unroll
    for (int j = 0; j < 4; j++) v[j] = tanhf(v[j]);
    ((f32x4*)dst)[i] = v;
}

// =====================================================================
// build m = concat(mem, inp) : m is (BATCH*9, 1024)
// =====================================================================
__global__ void k_build_m(float* __restrict__ m, const float* __restrict__ mem,
                          const float* __restrict__ inp, int inp_bstride) {
    int i = blockIdx.x * 256 + threadIdx.x;
    int e = i << 2;
    int c = e & 1023;
    int r = e >> 10;
    int b = r / 9, s = r - b * 9;
    f32x4 v;
    if (s < 8) v = *(const f32x4*)(mem + (((size_t)(b * 8 + s)) << 10) + c);
    else       v = *(const f32x4*)(inp + (size_t)b * inp_bstride + c);
    *(f32x4*)(m + (((size_t)r) << 10) + c) = v;
}

// =====================================================================
// split-3 bf16 MFMA GEMM (~f32 precision):
// C(MxN) = A(MxK,f32) * B^T + bias, B given as 3 planes (N x K) bf16.
// 128x128 tile, BK=32, 256 threads (4 waves, 2x2). ACT: 0=none 1=relu
// =====================================================================
template <int ACT>
__global__ __launch_bounds__(256) void k_gemm3(
    const float* __restrict__ A, long lda,
    const __bf16* __restrict__ BH, const __bf16* __restrict__ BM,
    const __bf16* __restrict__ BL,
    const float* __restrict__ bias,
    float* __restrict__ C, long ldc,
    int K) {
    __shared__ __bf16 Ah[128][40], Am[128][40], Al[128][40];
    __shared__ __bf16 Bh[128][40], Bm[128][40], Bl[128][40];
    const int row0 = blockIdx.x * 128;
    const int col0 = blockIdx.y * 128;
    const int tid  = threadIdx.x;
    const int lane = tid & 63;
    const int w    = tid >> 6;
    const int wr   = w >> 1, wc = w & 1;

    f32x4 acc[4][4] = {};

    const int srow = tid >> 1;          // 0..127
    const int sks  = (tid & 1) * 16;    // 0 or 16

    const float*  Aptr  = A  + (size_t)(row0 + srow) * lda + sks;
    const size_t  boff  = (size_t)(col0 + srow) * K + sks;

    const int kg   = (lane >> 4) * 8;
    const int rsel = lane & 15;

    for (int k0 = 0; k0 < K; k0 += 32) {
        __syncthreads();
        // ---- stage A (f32 -> 3x bf16 planes) ----
        f32x4 a0 = *(const f32x4*)(Aptr + k0 + 0);
        f32x4 a1 = *(const f32x4*)(Aptr + k0 + 4);
        f32x4 a2 = *(const f32x4*)(Aptr + k0 + 8);
        f32x4 a3 = *(const f32x4*)(Aptr + k0 + 12);
        bf16x8 h0, h1, m0, m1, l0, l1;
        #pragma unroll
        for (int j = 0; j < 4; j++) {
            __bf16 h, m, l;
            split3(a0[j], h, m, l); h0[j]     = h; m0[j]     = m; l0[j]     = l;
            split3(a1[j], h, m, l); h0[j + 4] = h; m0[j + 4] = m; l0[j + 4] = l;
            split3(a2[j], h, m, l); h1[j]     = h; m1[j]     = m; l1[j]     = l;
            split3(a3[j], h, m, l); h1[j + 4] = h; m1[j + 4] = m; l1[j + 4] = l;
        }
        *(bf16x8*)&Ah[srow][sks]     = h0;  *(bf16x8*)&Ah[srow][sks + 8] = h1;
        *(bf16x8*)&Am[srow][sks]     = m0;  *(bf16x8*)&Am[srow][sks + 8] = m1;
        *(bf16x8*)&Al[srow][sks]     = l0;  *(bf16x8*)&Al[srow][sks + 8] = l1;
        // ---- stage B (pre-split planes) ----
        {
            bf16x8 t0 = *(const bf16x8*)(BH + boff + k0);
            bf16x8 t1 = *(const bf16x8*)(BH + boff + k0 + 8);
            *(bf16x8*)&Bh[srow][sks] = t0; *(bf16x8*)&Bh[srow][sks + 8] = t1;
            t0 = *(const bf16x8*)(BM + boff + k0);
            t1 = *(const bf16x8*)(BM + boff + k0 + 8);
            *(bf16x8*)&Bm[srow][sks] = t0; *(bf16x8*)&Bm[srow][sks + 8] = t1;
            t0 = *(const bf16x8*)(BL + boff + k0);
            t1 = *(const bf16x8*)(BL + boff + k0 + 8);
            *(bf16x8*)&Bl[srow][sks] = t0; *(bf16x8*)&Bl[srow][sks + 8] = t1;
        }
        __syncthreads();

        bf16x8 ah[4], am[4], al[4], bh[4], bm[4], bl[4];
        #pragma unroll
        for (int mm = 0; mm < 4; mm++) {
            int r = wr * 64 + mm * 16 + rsel;
            ah[mm] = *(const bf16x8*)&Ah[r][kg];
            am[mm] = *(const bf16x8*)&Am[r][kg];
            al[mm] = *(const bf16x8*)&Al[r][kg];
        }
        #pragma unroll
        for (int nn = 0; nn < 4; nn++) {
            int r = wc * 64 + nn * 16 + rsel;
            bh[nn] = *(const bf16x8*)&Bh[r][kg];
            bm[nn] = *(const bf16x8*)&Bm[r][kg];
            bl[nn] = *(const bf16x8*)&Bl[r][kg];
        }
        #pragma unroll
        for (int mm = 0; mm < 4; mm++) {
            #pragma unroll
            for (int nn = 0; nn < 4; nn++) {
                f32x4 c = acc[mm][nn];
                // smallest terms first (~2^-18), then ~2^-9, then O(1)
                c = __builtin_amdgcn_mfma_f32_16x16x32_bf16(al[mm], bh[nn], c, 0, 0, 0);
                c = __builtin_amdgcn_mfma_f32_16x16x32_bf16(ah[mm], bl[nn], c, 0, 0, 0);
                c = __builtin_amdgcn_mfma_f32_16x16x32_bf16(am[mm], bm[nn], c, 0, 0, 0);
                c = __builtin_amdgcn_mfma_f32_16x16x32_bf16(am[mm], bh[nn], c, 0, 0, 0);
                c = __builtin_amdgcn_mfma_f32_16x16x32_bf16(ah[mm], bm[nn], c, 0, 0, 0);
                c = __builtin_amdgcn_mfma_f32_16x16x32_bf16(ah[mm], bh[nn], c, 0, 0, 0);
                acc[mm][nn] = c;
            }
        }
    }

    const int r_in = (lane >> 4) * 4;
    const int c_in = lane & 15;
    #pragma unroll
    for (int mm = 0; mm < 4; mm++) {
        #pragma unroll
        for (int nn = 0; nn < 4; nn++) {
            int col = col0 + wc * 64 + nn * 16 + c_in;
            float bv = bias[col];
            #pragma unroll
            for (int j = 0; j < 4; j++) {
                int row = row0 + wr * 64 + mm * 16 + r_in + j;
                float v = acc[mm][nn][j] + bv;
                if (ACT == 1) v = fmaxf(v, 0.f);
                C[(size_t)row * ldc + col] = v;
            }
        }
    }
}

// =====================================================================
// LayerNorm over (S1*C) per batch, in-place. grid = BATCH, 256 threads.
// =====================================================================
__global__ __launch_bounds__(256) void k_ln(float* __restrict__ x,
                                            const float* __restrict__ g,
                                            const float* __restrict__ bb, int SC) {
    const int b = blockIdx.x;
    float* p = x + (size_t)b * SC;
    const int tid = threadIdx.x;
    float s = 0.f, ss = 0.f;
    for (int i = tid * 4; i < SC; i += 1024) {
        f32x4 v = *(const f32x4*)(p + i);
        s  += v[0] + v[1] + v[2] + v[3];
        ss += v[0]*v[0] + v[1]*v[1] + v[2]*v[2] + v[3]*v[3];
    }
    #pragma unroll
    for (int off = 32; off > 0; off >>= 1) {
        s  += __shfl_down(s,  off, 64);
        ss += __shfl_down(ss, off, 64);
    }
    __shared__ float rs[4], rss[4];
    int wv = tid >> 6;
    if ((tid & 63) == 0) { rs[wv] = s; rss[wv] = ss; }
    __syncthreads();
    float S  = rs[0] + rs[1] + rs[2] + rs[3];
    float SS = rss[0] + rss[1] + rss[2] + rss[3];
    float invn = 1.f / (float)SC;
    float mean = S * invn;
    float var  = SS * invn - mean * mean;
    float rstd = rsqrtf(var + 1e-5f);
    for (int i = tid * 4; i < SC; i += 1024) {
        f32x4 v  = *(const f32x4*)(p + i);
        f32x4 gg = *(const f32x4*)(g + i);
        f32x4 bv = *(const f32x4*)(bb + i);
        v = (v - mean) * rstd;
        v = v * gg + bv;
        *(f32x4*)(p + i) = v;
    }
}

// =====================================================================
// m = LN(m + o) over (9*1024) per batch. grid = BATCH, 256 threads.
// =====================================================================
__global__ __launch_bounds__(256) void k_add_ln(float* __restrict__ m,
                                                const float* __restrict__ o,
                                                const float* __restrict__ g,
                                                const float* __restrict__ bb) {
    __shared__ float xs[9216];
    __shared__ float rs[4], rss[4];
    const int b = blockIdx.x;
    float* p = m + (size_t)b * 9216;
    const float* q = o + (size_t)b * 9216;
    const int tid = threadIdx.x;
    float s = 0.f, ss = 0.f;
    for (int i = tid * 4; i < 9216; i += 1024) {
        f32x4 v = *(const f32x4*)(p + i);
        f32x4 u = *(const f32x4*)(q + i);
        v += u;
        *(f32x4*)(xs + i) = v;
        s  += v[0] + v[1] + v[2] + v[3];
        ss += v[0]*v[0] + v[1]*v[1] + v[2]*v[2] + v[3]*v[3];
    }
    #pragma unroll
    for (int off = 32; off > 0; off >>= 1) {
        s  += __shfl_down(s,  off, 64);
        ss += __shfl_down(ss, off, 64);
    }
    int wv = tid >> 6;
    if ((tid & 63) == 0) { rs[wv] = s; rss[wv] = ss; }
    __syncthreads();
    float S  = rs[0] + rs[1] + rs[2] + rs[3];
    float SS = rss[0] + rss[1] + rss[2] + rss[3];
    const float invn = 1.f / 9216.f;
    float mean = S * invn;
    float var  = SS * invn - mean * mean;
    float rstd = rsqrtf(var + 1e-5f);
    for (int i = tid * 4; i < 9216; i += 1024) {
        f32x4 v  = *(const f32x4*)(xs + i);
        f32x4 gg = *(const f32x4*)(g + i);
        f32x4 bv = *(const f32x4*)(bb + i);
        v = (v - mean) * rstd;
        v = v * gg + bv;
        *(f32x4*)(p + i) = v;
    }
}

// =====================================================================
// attention per (b,h). grid = BATCH*8, 128 threads
// =====================================================================
__global__ __launch_bounds__(128) void k_attn(const float* __restrict__ qkv,
                                              float* __restrict__ att_out) {
    int bh = blockIdx.x;
    int b = bh >> 3, h = bh & 7;
    __shared__ float qs[9][128], ks[9][128], vs[9][128];
    __shared__ float att[9][12];
    int t = threadIdx.x;
    const float scale = 0.08838834764831845f;  // 128^-0.5
    #pragma unroll
    for (int s = 0; s < 9; s++) {
        const float* base = qkv + (size_t)(b * 9 + s) * 3072 + h * 384;
        qs[s][t] = base[t] * scale;
        ks[s][t] = base[128 + t];
        vs[s][t] = base[256 + t];
    }
    __syncthreads();
    if (t < 81) {
        int qi = t / 9, ki = t - qi * 9;
        float d = 0.f;
        #pragma unroll 8
        for (int c = 0; c < 128; c++) d += qs[qi][c] * ks[ki][c];
        att[qi][ki] = d;
    }
    __syncthreads();
    if (t < 9) {
        float mx = att[t][0];
        #pragma unroll
        for (int j = 1; j < 9; j++) mx = fmaxf(mx, att[t][j]);
        float e[9]; float sum = 0.f;
        #pragma unroll
        for (int j = 0; j < 9; j++) { e[j] = expf(att[t][j] - mx); sum += e[j]; }
        float inv = 1.f / sum;
        #pragma unroll
        for (int j = 0; j < 9; j++) att[t][j] = e[j] * inv;
    }
    __syncthreads();
    #pragma unroll
    for (int qi = 0; qi < 9; qi++) {
        float ov = 0.f;
        #pragma unroll
        for (int ki = 0; ki < 9; ki++) ov += att[qi][ki] * vs[ki][t];
        att_out[(size_t)(b * 9 + qi) * 1024 + h * 128 + t] = ov;
    }
}

// =====================================================================
// gating
// =====================================================================
__global__ void k_gate(const float* __restrict__ m, float* __restrict__ mem,
                       const float* __restrict__ gmem,
                       const float* __restrict__ ginp, int ginp_bstride,
                       const float* __restrict__ fb, const float* __restrict__ ib,
                       float* __restrict__ out) {
    int i = blockIdx.x * 256 + threadIdx.x;
    int e = i << 2;
    int c = e & 1023;
    int r = e >> 10;
    int b = r >> 3, s = r & 7;
    float FB = *fb, IB = *ib;
    f32x4 g1   = *(const f32x4*)(gmem + (size_t)r * 2048 + c);
    f32x4 g2   = *(const f32x4*)(gmem + (size_t)r * 2048 + 1024 + c);
    f32x4 i1   = *(const f32x4*)(ginp + (size_t)b * ginp_bstride + c);
    f32x4 i2   = *(const f32x4*)(ginp + (size_t)b * ginp_bstride + 1024 + c);
    f32x4 cand = *(const f32x4*)(m + (((size_t)(b * 9 + s)) << 10) + c);
    f32x4 old  = *(const f32x4*)(mem + (((size_t)r) << 10) + c);
    f32x4 o;
    #pragma unroll
    for (int j = 0; j < 4; j++) {
        float igv = 1.f / (1.f + expf(-(g1[j] + i1[j] + IB)));
        float fgv = 1.f / (1.f + expf(-(g2[j] + i2[j] + FB)));
        o[j] = igv * tanhf(cand[j]) + fgv * old[j];
    }
    *(f32x4*)(mem + (((size_t)r) << 10) + c) = o;
    *(f32x4*)(out + (size_t)b * 8192 + s * 1024 + c) = o;
}

// =====================================================================
// host launcher
// =====================================================================
extern "C" void kernel_launch(void* const* d_in, const int* in_sizes, int n_in,
                              void* d_out, int out_size, void* d_ws, size_t ws_size,
                              hipStream_t stream) {
    const float* inputs = (const float*)d_in[0];
    const float* memory = (const float*)d_in[1];
    const float* W_qkv  = (const float*)d_in[2];
    const float* b_qkv  = (const float*)d_in[3];
    const float* g_qln  = (const float*)d_in[4];
    const float* b_qln  = (const float*)d_in[5];
    const float* W_mlp  = (const float*)d_in[6];
    const float* b_mlp  = (const float*)d_in[7];
    const float* g_ln1  = (const float*)d_in[8];
    const float* b_ln1  = (const float*)d_in[9];
    const float* g_ln2  = (const float*)d_in[10];
    const float* b_ln2  = (const float*)d_in[11];
    const float* W_in   = (const float*)d_in[12];
    const float* b_in   = (const float*)d_in[13];
    const float* W_ig   = (const float*)d_in[14];
    const float* b_ig   = (const float*)d_in[15];
    const float* W_mg   = (const float*)d_in[16];
    const float* b_mg   = (const float*)d_in[17];
    const float* fb     = (const float*)d_in[18];
    const float* ib     = (const float*)d_in[19];
    float* out = (float*)d_out;

    char* ws = (char*)d_ws;
    size_t off = 0;
    auto alloc = [&](size_t bytes) -> char* {
        char* p = ws + off;
        off += (bytes + 255) & ~(size_t)255;
        return p;
    };
    // 3-plane split weights (H | M | L contiguous per weight)
    const size_t NE_in = (size_t)1024 * 1024, NE_qkv = (size_t)3072 * 1024,
                 NE_mlp = (size_t)1024 * 1024, NE_ig = (size_t)2048 * 1024,
                 NE_mg = (size_t)2048 * 1024;
    __bf16* WinS  = (__bf16*)alloc(NE_in  * 3 * 2);
    __bf16* WqkvS = (__bf16*)alloc(NE_qkv * 3 * 2);
    __bf16* WmlpS = (__bf16*)alloc(NE_mlp * 3 * 2);
    __bf16* WigS  = (__bf16*)alloc(NE_ig  * 3 * 2);
    __bf16* WmgS  = (__bf16*)alloc(NE_mg  * 3 * 2);
    float* mem_ws  = (float*)alloc((size_t)2048 * 1024 * 4);
    float* mbuf    = (float*)alloc((size_t)2304 * 1024 * 4);
    float* attout  = (float*)alloc((size_t)2304 * 1024 * 4);
    float* qkvbuf  = (float*)alloc((size_t)2304 * 3072 * 4);
    float* tmem    = (float*)alloc((size_t)2048 * 1024 * 4);
    float* inp_step  = (float*)alloc((size_t)256 * 1024 * 4);
    float* ginp_step = (float*)alloc((size_t)256 * 2048 * 4);
    size_t big_bytes = (size_t)8192 * 1024 * 4 + (size_t)8192 * 2048 * 4 + 4096;
    bool big = (ws_size >= off + big_bytes);
    float* inp_all = nullptr, *ginp_all = nullptr;
    if (big) {
        inp_all  = (float*)alloc((size_t)8192 * 1024 * 4);
        ginp_all = (float*)alloc((size_t)8192 * 2048 * 4);
    }
    float* h1   = qkvbuf;  // reuse (qkv dead after attention)
    float* gmem = qkvbuf;  // reuse (h1 dead after second MLP gemm)

    // --- one-time: weight split-transposes, mem copy, input projections ---
    dim3 tb(32, 8);
    k_transpose_split3<<<dim3(32, 32), tb, 0, stream>>>(W_in,  WinS,  WinS + NE_in,  WinS + 2*NE_in,  1024, 1024);
    k_transpose_split3<<<dim3(32, 96), tb, 0, stream>>>(W_qkv, WqkvS, WqkvS + NE_qkv, WqkvS + 2*NE_qkv, 3072, 1024);
    k_transpose_split3<<<dim3(32, 32), tb, 0, stream>>>(W_mlp, WmlpS, WmlpS + NE_mlp, WmlpS + 2*NE_mlp, 1024, 1024);
    k_transpose_split3<<<dim3(32, 64), tb, 0, stream>>>(W_ig,  WigS,  WigS + NE_ig,  WigS + 2*NE_ig,  2048, 1024);
    k_transpose_split3<<<dim3(32, 64), tb, 0, stream>>>(W_mg,  WmgS,  WmgS + NE_mg,  WmgS + 2*NE_mg,  2048, 1024);
    k_copy<<<2048, 256, 0, stream>>>(memory, mem_ws, 524288);
    if (big) {
        k_gemm3<0><<<dim3(64, 8),  256, 0, stream>>>(inputs,  1024, WinS, WinS + NE_in, WinS + 2*NE_in, b_in, inp_all,  1024, 1024);
        k_gemm3<0><<<dim3(64, 16), 256, 0, stream>>>(inp_all, 1024, WigS, WigS + NE_ig, WigS + 2*NE_ig, b_ig, ginp_all, 2048, 1024);
    }

    for (int t = 0; t < SEQT; t++) {
        const float* inpb;  int inps;
        const float* ginpb; int ginps;
        if (big) {
            inpb  = inp_all  + (size_t)t * 1024; inps  = SEQT * 1024;
            ginpb = ginp_all + (size_t)t * 2048; ginps = SEQT * 2048;
        } else {
            k_gemm3<0><<<dim3(2, 8),  256, 0, stream>>>(inputs + (size_t)t * 1024, SEQT * 1024, WinS, WinS + NE_in, WinS + 2*NE_in, b_in, inp_step, 1024, 1024);
            k_gemm3<0><<<dim3(2, 16), 256, 0, stream>>>(inp_step, 1024, WigS, WigS + NE_ig, WigS + 2*NE_ig, b_ig, ginp_step, 2048, 1024);
            inpb = inp_step; inps = 1024; ginpb = ginp_step; ginps = 2048;
        }
        k_build_m<<<2304, 256, 0, stream>>>(mbuf, mem_ws, inpb, inps);
        k_gemm3<0><<<dim3(18, 24), 256, 0, stream>>>(mbuf, 1024, WqkvS, WqkvS + NE_qkv, WqkvS + 2*NE_qkv, b_qkv, qkvbuf, 3072, 1024);
        k_ln<<<BATCH, 256, 0, stream>>>(qkvbuf, g_qln, b_qln, S1 * TOTAL_QKV);
        k_attn<<<BATCH * 8, 128, 0, stream>>>(qkvbuf, attout);
        k_add_ln<<<BATCH, 256, 0, stream>>>(mbuf, attout, g_ln1, b_ln1);
        k_gemm3<1><<<dim3(18, 8), 256, 0, stream>>>(mbuf, 1024, WmlpS, WmlpS + NE_mlp, WmlpS + 2*NE_mlp, b_mlp, h1, 1024, 1024);
        k_gemm3<1><<<dim3(18, 8), 256, 0, stream>>>(h1, 1024, WmlpS, WmlpS + NE_mlp, WmlpS + 2*NE_mlp, b_mlp, attout, 1024, 1024);
        k_add_ln<<<BATCH, 256, 0, stream>>>(mbuf, attout, g_ln2, b_ln2);
        k_tanh<<<2048, 256, 0, stream>>>(mem_ws, tmem, 524288);
        k_gemm3<0><<<dim3(16, 16), 256, 0, stream>>>(tmem, 1024, WmgS, WmgS + NE_mg, WmgS + 2*NE_mg, b_mg, gmem, 2048, 1024);
        k_gate<<<2048, 256, 0, stream>>>(mbuf, mem_ws, gmem, ginpb, ginps, fb, ib,
                                         out + (size_t)t * (BATCH * 8192));
    }
    // final_mem
    k_copy<<<2048, 256, 0, stream>>>(mem_ws, out + (size_t)SEQT * BATCH * 8192, 524288);
}

// Round 3
// 8588.747 us; speedup vs baseline: 1.4643x; 1.4643x over previous
//
#include <hip/hip_runtime.h>
#include <hip/hip_bf16.h>
#include <cstdint>
#include <cstddef>

// ---------------- types ----------------
typedef float    f32x4 __attribute__((ext_vector_type(4)));
typedef _Float16 f16x8 __attribute__((ext_vector_type(8)));
typedef _Float16 f16x4 __attribute__((ext_vector_type(4)));

#define BATCH 256
#define SEQT  32
#define S1    9

__device__ __forceinline__ void split2(float a, _Float16& h, _Float16& m) {
    h = (_Float16)a;
    m = (_Float16)(a - (float)h);
}

__device__ __forceinline__ void gload_lds16(const void* g, void* l) {
    __builtin_amdgcn_global_load_lds(
        (const __attribute__((address_space(1))) unsigned int*)g,
        (__attribute__((address_space(3))) unsigned int*)l, 16, 0, 0);
}

// =====================================================================
// Weight transpose + 2-way fp16 split: W (K x N) f32 -> H/M (N x K) fp16
// grid(K/32, N/32), block(32,8)
// =====================================================================
__global__ void k_transpose_split2(const float* __restrict__ W,
                                   _Float16* __restrict__ H, _Float16* __restrict__ M,
                                   int N, int K) {
    __shared__ float tile[32][33];
    int k0 = blockIdx.x * 32, n0 = blockIdx.y * 32;
    int tx = threadIdx.x, ty = threadIdx.y;
    #pragma unroll
    for (int i = ty; i < 32; i += 8)
        tile[i][tx] = W[(size_t)(k0 + i) * N + (n0 + tx)];
    __syncthreads();
    #pragma unroll
    for (int i = ty; i < 32; i += 8) {
        float a = tile[tx][i];
        _Float16 h, m; split2(a, h, m);
        size_t idx = (size_t)(n0 + i) * K + (k0 + tx);
        H[idx] = h; M[idx] = m;
    }
}

// =====================================================================
// split rows of f32 matrix (row stride s_in) into contiguous fp16 planes
// [R][1024]. n4 = R*256 vec4 elems.
// =====================================================================
__global__ void k_split2_rows(const float* __restrict__ src, long s_in,
                              _Float16* __restrict__ H, _Float16* __restrict__ M,
                              int n4) {
    int i = blockIdx.x * 256 + threadIdx.x;
    if (i >= n4) return;
    int e = i << 2;
    int c = e & 1023;
    int r = e >> 10;
    f32x4 v = *(const f32x4*)(src + (size_t)r * s_in + c);
    f16x4 h, m;
    #pragma unroll
    for (int j = 0; j < 4; j++) { _Float16 hh, mm; split2(v[j], hh, mm); h[j] = hh; m[j] = mm; }
    size_t o = ((size_t)r << 10) + c;
    *(f16x4*)(H + o) = h;
    *(f16x4*)(M + o) = m;
}

// =====================================================================
// vec4 copy
// =====================================================================
__global__ void k_copy(const float* __restrict__ src, float* __restrict__ dst, int n4) {
    int i = blockIdx.x * 256 + threadIdx.x;
    if (i < n4) ((f32x4*)dst)[i] = ((const f32x4*)src)[i];
}

// =====================================================================
// tanh(mem) -> fp16 planes (2048 x 1024)
// =====================================================================
__global__ void k_tanh_split(const float* __restrict__ src,
                             _Float16* __restrict__ H, _Float16* __restrict__ M, int n4) {
    int i = blockIdx.x * 256 + threadIdx.x;
    if (i >= n4) return;
    f32x4 v = ((const f32x4*)src)[i];
    f16x4 h, m;
    #pragma unroll
    for (int j = 0; j < 4; j++) {
        float t = tanhf(v[j]);
        _Float16 hh, mm; split2(t, hh, mm); h[j] = hh; m[j] = mm;
    }
    *(f16x4*)(H + ((size_t)i << 2)) = h;
    *(f16x4*)(M + ((size_t)i << 2)) = m;
}

// =====================================================================
// build m = concat(mem, inp) -> mbuf f32 (2304x1024) + fp16 planes
// =====================================================================
__global__ void k_build_m_split(float* __restrict__ m,
                                _Float16* __restrict__ H, _Float16* __restrict__ M,
                                const float* __restrict__ mem,
                                const float* __restrict__ inp, long inp_bstride) {
    int i = blockIdx.x * 256 + threadIdx.x;   // vec4 over 2304*1024
    int e = i << 2;
    int c = e & 1023;
    int r = e >> 10;
    int b = r / 9, s = r - b * 9;
    f32x4 v;
    if (s < 8) v = *(const f32x4*)(mem + (((size_t)(b * 8 + s)) << 10) + c);
    else       v = *(const f32x4*)(inp + (size_t)b * inp_bstride + c);
    size_t o = (((size_t)r) << 10) + c;
    *(f32x4*)(m + o) = v;
    f16x4 h, mm_;
    #pragma unroll
    for (int j = 0; j < 4; j++) { _Float16 hh, mm; split2(v[j], hh, mm); h[j] = hh; mm_[j] = mm; }
    *(f16x4*)(H + o) = h;
    *(f16x4*)(M + o) = mm_;
}

// =====================================================================
// fp16 split-2 MFMA GEMM (4 terms, ~2^-22 precision):
// C(MxN) = A * B^T + bias. A planes [M][1024], B planes [N][1024] fp16.
// 128x128 tile, BK=32, 256 thr (4 waves 2x2). global_load_lds staging with
// source-swizzled linear LDS (chunk' = kc ^ ((row>>1)&3)).
// RELU: relu epilogue. WF32: write f32 C. WPL: write fp16 split planes.
// =====================================================================
template <int RELU, int WF32, int WPL>
__global__ __launch_bounds__(256) void k_gemm2(
    const _Float16* __restrict__ APh, const _Float16* __restrict__ APm,
    const _Float16* __restrict__ BPh, const _Float16* __restrict__ BPm,
    const float* __restrict__ bias,
    float* __restrict__ C, long ldc,
    _Float16* __restrict__ Ph, _Float16* __restrict__ Pm) {
    __shared__ __align__(16) char smem[32768];  // 4 slabs x 8KB: Ah Am Bh Bm
    const int row0 = blockIdx.x * 128;
    const int col0 = blockIdx.y * 128;
    const int tid  = threadIdx.x;
    const int l    = tid & 63;
    const int w    = tid >> 6;
    const int wr   = w >> 1, wc = w & 1;

    f32x4 acc[4][4] = {};

    // ---- staging addresses ----
    const int r_l = w * 32 + (l >> 2);                 // row covered by this lane (issue 0)
    const int kc  = (l & 3) ^ ((l >> 3) & 3);          // inverse-swizzled source chunk
    const _Float16* aH = APh + (size_t)(row0 + r_l) * 1024 + kc * 8;
    const _Float16* aM = APm + (size_t)(row0 + r_l) * 1024 + kc * 8;
    const _Float16* bH = BPh + (size_t)(col0 + r_l) * 1024 + kc * 8;
    const _Float16* bM = BPm + (size_t)(col0 + r_l) * 1024 + kc * 8;
    char* d0 = smem + w * 2048;

    // ---- frag read offsets (swizzled) ----
    const int kcsel = l >> 4, rsel = l & 15;
    const int swz   = (kcsel ^ ((rsel >> 1) & 3)) * 16;
    const int offA  = (wr * 64 + rsel) * 64 + swz;     // + mm*1024
    const int offB  = (wc * 64 + rsel) * 64 + swz;     // + nn*1024

    #pragma unroll 2
    for (int k0 = 0; k0 < 1024; k0 += 32) {
        gload_lds16(aH + k0,         d0);
        gload_lds16(aH + k0 + 16384, d0 + 1024);
        gload_lds16(aM + k0,         d0 + 8192);
        gload_lds16(aM + k0 + 16384, d0 + 9216);
        gload_lds16(bH + k0,         d0 + 16384);
        gload_lds16(bH + k0 + 16384, d0 + 17408);
        gload_lds16(bM + k0,         d0 + 24576);
        gload_lds16(bM + k0 + 16384, d0 + 25600);
        __syncthreads();

        f16x8 ah[4], am[4], bh[4], bm[4];
        #pragma unroll
        for (int mm = 0; mm < 4; mm++) {
            ah[mm] = *(const f16x8*)(smem + offA + mm * 1024);
            am[mm] = *(const f16x8*)(smem + 8192 + offA + mm * 1024);
        }
        #pragma unroll
        for (int nn = 0; nn < 4; nn++) {
            bh[nn] = *(const f16x8*)(smem + 16384 + offB + nn * 1024);
            bm[nn] = *(const f16x8*)(smem + 24576 + offB + nn * 1024);
        }
        #pragma unroll
        for (int mm = 0; mm < 4; mm++) {
            #pragma unroll
            for (int nn = 0; nn < 4; nn++) {
                f32x4 c = acc[mm][nn];
                c = __builtin_amdgcn_mfma_f32_16x16x32_f16(am[mm], bm[nn], c, 0, 0, 0);
                c = __builtin_amdgcn_mfma_f32_16x16x32_f16(am[mm], bh[nn], c, 0, 0, 0);
                c = __builtin_amdgcn_mfma_f32_16x16x32_f16(ah[mm], bm[nn], c, 0, 0, 0);
                c = __builtin_amdgcn_mfma_f32_16x16x32_f16(ah[mm], bh[nn], c, 0, 0, 0);
                acc[mm][nn] = c;
            }
        }
        __syncthreads();
    }

    const int r_in = (l >> 4) * 4;
    const int c_in = l & 15;
    #pragma unroll
    for (int mm = 0; mm < 4; mm++) {
        #pragma unroll
        for (int nn = 0; nn < 4; nn++) {
            int col = col0 + wc * 64 + nn * 16 + c_in;
            float bv = bias[col];
            #pragma unroll
            for (int j = 0; j < 4; j++) {
                int row = row0 + wr * 64 + mm * 16 + r_in + j;
                float v = acc[mm][nn][j] + bv;
                if (RELU) v = fmaxf(v, 0.f);
                size_t o = (size_t)row * ldc + col;
                if (WF32) C[o] = v;
                if (WPL) {
                    _Float16 h, m; split2(v, h, m);
                    Ph[o] = h; Pm[o] = m;
                }
            }
        }
    }
}

// =====================================================================
// LayerNorm over (S1*C) per batch, in-place. grid = BATCH, 256 threads.
// =====================================================================
__global__ __launch_bounds__(256) void k_ln(float* __restrict__ x,
                                            const float* __restrict__ g,
                                            const float* __restrict__ bb, int SC) {
    const int b = blockIdx.x;
    float* p = x + (size_t)b * SC;
    const int tid = threadIdx.x;
    float s = 0.f, ss = 0.f;
    for (int i = tid * 4; i < SC; i += 1024) {
        f32x4 v = *(const f32x4*)(p + i);
        s  += v[0] + v[1] + v[2] + v[3];
        ss += v[0]*v[0] + v[1]*v[1] + v[2]*v[2] + v[3]*v[3];
    }
    #pragma unroll
    for (int off = 32; off > 0; off >>= 1) {
        s  += __shfl_down(s,  off, 64);
        ss += __shfl_down(ss, off, 64);
    }
    __shared__ float rs[4], rss[4];
    int wv = tid >> 6;
    if ((tid & 63) == 0) { rs[wv] = s; rss[wv] = ss; }
    __syncthreads();
    float S  = rs[0] + rs[1] + rs[2] + rs[3];
    float SS = rss[0] + rss[1] + rss[2] + rss[3];
    float invn = 1.f / (float)SC;
    float mean = S * invn;
    float var  = SS * invn - mean * mean;
    float rstd = rsqrtf(var + 1e-5f);
    for (int i = tid * 4; i < SC; i += 1024) {
        f32x4 v  = *(const f32x4*)(p + i);
        f32x4 gg = *(const f32x4*)(g + i);
        f32x4 bv = *(const f32x4*)(bb + i);
        v = (v - mean) * rstd;
        v = v * gg + bv;
        *(f32x4*)(p + i) = v;
    }
}

// =====================================================================
// m = LN(m + o) over (9*1024) per batch; optionally emit fp16 planes.
// =====================================================================
template <int WPL>
__global__ __launch_bounds__(256) void k_add_ln(float* __restrict__ m,
                                                const float* __restrict__ o,
                                                const float* __restrict__ g,
                                                const float* __restrict__ bb,
                                                _Float16* __restrict__ Ph,
                                                _Float16* __restrict__ Pm) {
    __shared__ float xs[9216];
    __shared__ float rs[4], rss[4];
    const int b = blockIdx.x;
    float* p = m + (size_t)b * 9216;
    const float* q = o + (size_t)b * 9216;
    const int tid = threadIdx.x;
    float s = 0.f, ss = 0.f;
    for (int i = tid * 4; i < 9216; i += 1024) {
        f32x4 v = *(const f32x4*)(p + i);
        f32x4 u = *(const f32x4*)(q + i);
        v += u;
        *(f32x4*)(xs + i) = v;
        s  += v[0] + v[1] + v[2] + v[3];
        ss += v[0]*v[0] + v[1]*v[1] + v[2]*v[2] + v[3]*v[3];
    }
    #pragma unroll
    for (int off = 32; off > 0; off >>= 1) {
        s  += __shfl_down(s,  off, 64);
        ss += __shfl_down(ss, off, 64);
    }
    int wv = tid >> 6;
    if ((tid & 63) == 0) { rs[wv] = s; rss[wv] = ss; }
    __syncthreads();
    float S  = rs[0] + rs[1] + rs[2] + rs[3];
    float SS = rss[0] + rss[1] + rss[2] + rss[3];
    const float invn = 1.f / 9216.f;
    float mean = S * invn;
    float var  = SS * invn - mean * mean;
    float rstd = rsqrtf(var + 1e-5f);
    for (int i = tid * 4; i < 9216; i += 1024) {
        f32x4 v  = *(const f32x4*)(xs + i);
        f32x4 gg = *(const f32x4*)(g + i);
        f32x4 bv = *(const f32x4*)(bb + i);
        v = (v - mean) * rstd;
        v = v * gg + bv;
        *(f32x4*)(p + i) = v;
        if (WPL) {
            f16x4 h, mm_;
            #pragma unroll
            for (int j = 0; j < 4; j++) { _Float16 hh, mm; split2(v[j], hh, mm); h[j] = hh; mm_[j] = mm; }
            size_t oo = (size_t)b * 9216 + i;
            *(f16x4*)(Ph + oo) = h;
            *(f16x4*)(Pm + oo) = mm_;
        }
    }
}

// =====================================================================
// attention per (b,h). grid = BATCH*8, 128 threads
// =====================================================================
__global__ __launch_bounds__(128) void k_attn(const float* __restrict__ qkv,
                                              float* __restrict__ att_out) {
    int bh = blockIdx.x;
    int b = bh >> 3, h = bh & 7;
    __shared__ float qs[9][128], ks[9][128], vs[9][128];
    __shared__ float att[9][12];
    int t = threadIdx.x;
    const float scale = 0.08838834764831845f;
    #pragma unroll
    for (int s = 0; s < 9; s++) {
        const float* base = qkv + (size_t)(b * 9 + s) * 3072 + h * 384;
        qs[s][t] = base[t] * scale;
        ks[s][t] = base[128 + t];
        vs[s][t] = base[256 + t];
    }
    __syncthreads();
    if (t < 81) {
        int qi = t / 9, ki = t - qi * 9;
        float d = 0.f;
        #pragma unroll 8
        for (int c = 0; c < 128; c++) d += qs[qi][c] * ks[ki][c];
        att[qi][ki] = d;
    }
    __syncthreads();
    if (t < 9) {
        float mx = att[t][0];
        #pragma unroll
        for (int j = 1; j < 9; j++) mx = fmaxf(mx, att[t][j]);
        float e[9]; float sum = 0.f;
        #pragma unroll
        for (int j = 0; j < 9; j++) { e[j] = expf(att[t][j] - mx); sum += e[j]; }
        float inv = 1.f / sum;
        #pragma unroll
        for (int j = 0; j < 9; j++) att[t][j] = e[j] * inv;
    }
    __syncthreads();
    #pragma unroll
    for (int qi = 0; qi < 9; qi++) {
        float ov = 0.f;
        #pragma unroll
        for (int ki = 0; ki < 9; ki++) ov += att[qi][ki] * vs[ki][t];
        att_out[(size_t)(b * 9 + qi) * 1024 + h * 128 + t] = ov;
    }
}

// =====================================================================
// gating
// =====================================================================
__global__ void k_gate(const float* __restrict__ m, float* __restrict__ mem,
                       const float* __restrict__ gmem,
                       const float* __restrict__ ginp, long ginp_bstride,
                       const float* __restrict__ fb, const float* __restrict__ ib,
                       float* __restrict__ out) {
    int i = blockIdx.x * 256 + threadIdx.x;
    int e = i << 2;
    int c = e & 1023;
    int r = e >> 10;
    int b = r >> 3, s = r & 7;
    float FB = *fb, IB = *ib;
    f32x4 g1   = *(const f32x4*)(gmem + (size_t)r * 2048 + c);
    f32x4 g2   = *(const f32x4*)(gmem + (size_t)r * 2048 + 1024 + c);
    f32x4 i1   = *(const f32x4*)(ginp + (size_t)b * ginp_bstride + c);
    f32x4 i2   = *(const f32x4*)(ginp + (size_t)b * ginp_bstride + 1024 + c);
    f32x4 cand = *(const f32x4*)(m + (((size_t)(b * 9 + s)) << 10) + c);
    f32x4 old  = *(const f32x4*)(mem + (((size_t)r) << 10) + c);
    f32x4 o;
    #pragma unroll
    for (int j = 0; j < 4; j++) {
        float igv = 1.f / (1.f + expf(-(g1[j] + i1[j] + IB)));
        float fgv = 1.f / (1.f + expf(-(g2[j] + i2[j] + FB)));
        o[j] = igv * tanhf(cand[j]) + fgv * old[j];
    }
    *(f32x4*)(mem + (((size_t)r) << 10) + c) = o;
    *(f32x4*)(out + (size_t)b * 8192 + s * 1024 + c) = o;
}

// =====================================================================
// host launcher
// =====================================================================
extern "C" void kernel_launch(void* const* d_in, const int* in_sizes, int n_in,
                              void* d_out, int out_size, void* d_ws, size_t ws_size,
                              hipStream_t stream) {
    const float* inputs = (const float*)d_in[0];
    const float* memory = (const float*)d_in[1];
    const float* W_qkv  = (const float*)d_in[2];
    const float* b_qkv  = (const float*)d_in[3];
    const float* g_qln  = (const float*)d_in[4];
    const float* b_qln  = (const float*)d_in[5];
    const float* W_mlp  = (const float*)d_in[6];
    const float* b_mlp  = (const float*)d_in[7];
    const float* g_ln1  = (const float*)d_in[8];
    const float* b_ln1  = (const float*)d_in[9];
    const float* g_ln2  = (const float*)d_in[10];
    const float* b_ln2  = (const float*)d_in[11];
    const float* W_in   = (const float*)d_in[12];
    const float* b_in   = (const float*)d_in[13];
    const float* W_ig   = (const float*)d_in[14];
    const float* b_ig   = (const float*)d_in[15];
    const float* W_mg   = (const float*)d_in[16];
    const float* b_mg   = (const float*)d_in[17];
    const float* fb     = (const float*)d_in[18];
    const float* ib     = (const float*)d_in[19];
    float* out = (float*)d_out;

    char* ws = (char*)d_ws;
    size_t off = 0;
    auto alloc = [&](size_t bytes) -> char* {
        char* p = ws + off;
        off += (bytes + 255) & ~(size_t)255;
        return p;
    };
    // weight planes (fp16, [N][K], H then M contiguous)
    const size_t NEin = (size_t)1024*1024, NEqkv = (size_t)3072*1024,
                 NEmlp = (size_t)1024*1024, NEig = (size_t)2048*1024, NEmg = (size_t)2048*1024;
    _Float16* WinP  = (_Float16*)alloc(NEin  * 2 * 2);
    _Float16* WqkvP = (_Float16*)alloc(NEqkv * 2 * 2);
    _Float16* WmlpP = (_Float16*)alloc(NEmlp * 2 * 2);
    _Float16* WigP  = (_Float16*)alloc(NEig  * 2 * 2);
    _Float16* WmgP  = (_Float16*)alloc(NEmg  * 2 * 2);

    float*    mem_ws = (float*)alloc((size_t)2048 * 1024 * 4);
    float*    mbuf   = (float*)alloc((size_t)2304 * 1024 * 4);
    _Float16* mbufP  = (_Float16*)alloc((size_t)2304 * 1024 * 2 * 2);
    float*    attout = (float*)alloc((size_t)2304 * 1024 * 4);
    float*    qkvbuf = (float*)alloc((size_t)2304 * 3072 * 4);
    _Float16* h1P    = (_Float16*)alloc((size_t)2304 * 1024 * 2 * 2);
    _Float16* tanhP  = (_Float16*)alloc((size_t)2048 * 1024 * 2 * 2);
    float*    gmem   = qkvbuf;  // alias: qkv dead after attention

    const size_t NEm  = (size_t)2304 * 1024;
    const size_t NEt  = (size_t)2048 * 1024;
    const size_t NEbig = (size_t)8192 * 1024;

    // big path: hoisted input projections
    size_t big_bytes = NEbig*2*2 /*inputsP*/ + NEbig*4 /*inp_all*/ + NEbig*2*2 /*inp_allP*/
                     + (size_t)8192*2048*4 /*ginp_all*/ + 8192;
    bool big = (ws_size >= off + big_bytes);
    _Float16 *inputsP = nullptr, *inp_allP = nullptr;
    float *inp_all = nullptr, *ginp_all = nullptr;
    // small path scratch
    _Float16 *inP_step = nullptr, *inp_stepP = nullptr;
    float *inp_step = nullptr, *ginp_step = nullptr;
    if (big) {
        inputsP  = (_Float16*)alloc(NEbig * 2 * 2);
        inp_all  = (float*)alloc(NEbig * 4);
        inp_allP = (_Float16*)alloc(NEbig * 2 * 2);
        ginp_all = (float*)alloc((size_t)8192 * 2048 * 4);
    } else {
        inP_step  = (_Float16*)alloc((size_t)256 * 1024 * 2 * 2);
        inp_step  = (float*)alloc((size_t)256 * 1024 * 4);
        inp_stepP = (_Float16*)alloc((size_t)256 * 1024 * 2 * 2);
        ginp_step = (float*)alloc((size_t)256 * 2048 * 4);
    }

    // --- one-time: weight split-transposes, mem copy, input projections ---
    dim3 tb(32, 8);
    k_transpose_split2<<<dim3(32, 32), tb, 0, stream>>>(W_in,  WinP,  WinP + NEin,  1024, 1024);
    k_transpose_split2<<<dim3(32, 96), tb, 0, stream>>>(W_qkv, WqkvP, WqkvP + NEqkv, 3072, 1024);
    k_transpose_split2<<<dim3(32, 32), tb, 0, stream>>>(W_mlp, WmlpP, WmlpP + NEmlp, 1024, 1024);
    k_transpose_split2<<<dim3(32, 64), tb, 0, stream>>>(W_ig,  WigP,  WigP + NEig,  2048, 1024);
    k_transpose_split2<<<dim3(32, 64), tb, 0, stream>>>(W_mg,  WmgP,  WmgP + NEmg,  2048, 1024);
    k_copy<<<2048, 256, 0, stream>>>(memory, mem_ws, 524288);
    if (big) {
        k_split2_rows<<<8192, 256, 0, stream>>>(inputs, 1024, inputsP, inputsP + NEbig, 8192 * 256);
        k_gemm2<0,1,1><<<dim3(64, 8), 256, 0, stream>>>(inputsP, inputsP + NEbig,
            WinP, WinP + NEin, b_in, inp_all, 1024, inp_allP, inp_allP + NEbig);
        k_gemm2<0,1,0><<<dim3(64, 16), 256, 0, stream>>>(inp_allP, inp_allP + NEbig,
            WigP, WigP + NEig, b_ig, ginp_all, 2048, nullptr, nullptr);
    }

    for (int t = 0; t < SEQT; t++) {
        const float* inpb;  long inps;
        const float* ginpb; long ginps;
        if (big) {
            inpb  = inp_all  + (size_t)t * 1024; inps  = SEQT * 1024;
            ginpb = ginp_all + (size_t)t * 2048; ginps = SEQT * 2048;
        } else {
            const size_t NEs = (size_t)256 * 1024;
            k_split2_rows<<<256, 256, 0, stream>>>(inputs + (size_t)t * 1024, (long)SEQT * 1024,
                                                   inP_step, inP_step + NEs, 256 * 256);
            k_gemm2<0,1,1><<<dim3(2, 8), 256, 0, stream>>>(inP_step, inP_step + NEs,
                WinP, WinP + NEin, b_in, inp_step, 1024, inp_stepP, inp_stepP + NEs);
            k_gemm2<0,1,0><<<dim3(2, 16), 256, 0, stream>>>(inp_stepP, inp_stepP + NEs,
                WigP, WigP + NEig, b_ig, ginp_step, 2048, nullptr, nullptr);
            inpb = inp_step; inps = 1024; ginpb = ginp_step; ginps = 2048;
        }
        k_build_m_split<<<2304, 256, 0, stream>>>(mbuf, mbufP, mbufP + NEm, mem_ws, inpb, inps);
        k_gemm2<0,1,0><<<dim3(18, 24), 256, 0, stream>>>(mbufP, mbufP + NEm,
            WqkvP, WqkvP + NEqkv, b_qkv, qkvbuf, 3072, nullptr, nullptr);
        k_ln<<<BATCH, 256, 0, stream>>>(qkvbuf, g_qln, b_qln, S1 * 3072);
        k_attn<<<BATCH * 8, 128, 0, stream>>>(qkvbuf, attout);
        k_add_ln<1><<<BATCH, 256, 0, stream>>>(mbuf, attout, g_ln1, b_ln1, mbufP, mbufP + NEm);
        k_gemm2<1,0,1><<<dim3(18, 8), 256, 0, stream>>>(mbufP, mbufP + NEm,
            WmlpP, WmlpP + NEmlp, b_mlp, nullptr, 1024, h1P, h1P + NEm);
        k_gemm2<1,1,0><<<dim3(18, 8), 256, 0, stream>>>(h1P, h1P + NEm,
            WmlpP, WmlpP + NEmlp, b_mlp, attout, 1024, nullptr, nullptr);
        k_add_ln<0><<<BATCH, 256, 0, stream>>>(mbuf, attout, g_ln2, b_ln2, nullptr, nullptr);
        k_tanh_split<<<2048, 256, 0, stream>>>(mem_ws, tanhP, tanhP + NEt, 524288);
        k_gemm2<0,1,0><<<dim3(16, 16), 256, 0, stream>>>(tanhP, tanhP + NEt,
            WmgP, WmgP + NEmg, b_mg, gmem, 2048, nullptr, nullptr);
        k_gate<<<2048, 256, 0, stream>>>(mbuf, mem_ws, gmem, ginpb, ginps, fb, ib,
                                         out + (size_t)t * (BATCH * 8192));
    }
    k_copy<<<2048, 256, 0, stream>>>(mem_ws, out + (size_t)SEQT * BATCH * 8192, 524288);
}

// Round 4
// 6847.849 us; speedup vs baseline: 1.8366x; 1.2542x over previous
//
#include <hip/hip_runtime.h>
#include <hip/hip_bf16.h>
#include <cstdint>
#include <cstddef>

// ---------------- types ----------------
typedef float    f32x4 __attribute__((ext_vector_type(4)));
typedef _Float16 f16x8 __attribute__((ext_vector_type(8)));
typedef _Float16 f16x4 __attribute__((ext_vector_type(4)));

#define BATCH 256
#define SEQT  32
#define S1    9

__device__ __forceinline__ void split2(float a, _Float16& h, _Float16& m) {
    h = (_Float16)a;
    m = (_Float16)(a - (float)h);
}
__device__ __forceinline__ float sigf(float x) { return 1.f / (1.f + expf(-x)); }

__device__ __forceinline__ void gload_lds16(const void* g, void* l) {
    __builtin_amdgcn_global_load_lds(
        (const __attribute__((address_space(1))) unsigned int*)g,
        (__attribute__((address_space(3))) unsigned int*)l, 16, 0, 0);
}

// block-wide (8 waves, 512 thr) sum of (s, ss); all threads end with totals
__device__ __forceinline__ void bred8(float& s, float& ss, float* red, int tid) {
    #pragma unroll
    for (int o = 32; o > 0; o >>= 1) {
        s  += __shfl_down(s,  o, 64);
        ss += __shfl_down(ss, o, 64);
    }
    __syncthreads();                       // also guards red[] reuse
    if ((tid & 63) == 0) { red[(tid >> 6) * 2] = s; red[(tid >> 6) * 2 + 1] = ss; }
    __syncthreads();
    s = 0.f; ss = 0.f;
    #pragma unroll
    for (int wv = 0; wv < 8; wv++) { s += red[wv * 2]; ss += red[wv * 2 + 1]; }
}

// =====================================================================
// Weight transpose + 2-way fp16 split: W (K x N) f32 -> H/M (N x K) fp16
// =====================================================================
__global__ void k_transpose_split2(const float* __restrict__ W,
                                   _Float16* __restrict__ H, _Float16* __restrict__ M,
                                   int N, int K) {
    __shared__ float tile[32][33];
    int k0 = blockIdx.x * 32, n0 = blockIdx.y * 32;
    int tx = threadIdx.x, ty = threadIdx.y;
    #pragma unroll
    for (int i = ty; i < 32; i += 8)
        tile[i][tx] = W[(size_t)(k0 + i) * N + (n0 + tx)];
    __syncthreads();
    #pragma unroll
    for (int i = ty; i < 32; i += 8) {
        float a = tile[tx][i];
        _Float16 h, m; split2(a, h, m);
        size_t idx = (size_t)(n0 + i) * K + (k0 + tx);
        H[idx] = h; M[idx] = m;
    }
}

// =====================================================================
// split rows of f32 matrix (row stride s_in) into fp16 planes [R][1024]
// =====================================================================
__global__ void k_split2_rows(const float* __restrict__ src, long s_in,
                              _Float16* __restrict__ H, _Float16* __restrict__ M,
                              int n4) {
    int i = blockIdx.x * 256 + threadIdx.x;
    if (i >= n4) return;
    int e = i << 2;
    int c = e & 1023;
    int r = e >> 10;
    f32x4 v = *(const f32x4*)(src + (size_t)r * s_in + c);
    f16x4 h, m;
    #pragma unroll
    for (int j = 0; j < 4; j++) { _Float16 hh, mm; split2(v[j], hh, mm); h[j] = hh; m[j] = mm; }
    size_t o = ((size_t)r << 10) + c;
    *(f16x4*)(H + o) = h;
    *(f16x4*)(M + o) = m;
}

__global__ void k_copy(const float* __restrict__ src, float* __restrict__ dst, int n4) {
    int i = blockIdx.x * 256 + threadIdx.x;
    if (i < n4) ((f32x4*)dst)[i] = ((const f32x4*)src)[i];
}

// =====================================================================
// step-0 prep: mbuf = concat(memory, inp0) (f32 + planes), mem_ws copy,
// tanh planes of memory. grid 2304 x 256 (vec4)
// =====================================================================
__global__ void k_prep0(float* __restrict__ mbuf,
                        _Float16* __restrict__ Ph, _Float16* __restrict__ Pm,
                        const float* __restrict__ memory, float* __restrict__ mem_ws,
                        _Float16* __restrict__ Th, _Float16* __restrict__ Tm,
                        const float* __restrict__ inp0, long inp_stride) {
    int i = blockIdx.x * 256 + threadIdx.x;
    int e = i << 2;
    int c = e & 1023;
    int r = e >> 10;
    int b = r / 9, s = r - b * 9;
    f32x4 v;
    if (s < 8) {
        size_t mo = (((size_t)(b * 8 + s)) << 10) + c;
        v = *(const f32x4*)(memory + mo);
        *(f32x4*)(mem_ws + mo) = v;
        f16x4 th, tm;
        #pragma unroll
        for (int j = 0; j < 4; j++) {
            float tv = tanhf(v[j]);
            _Float16 hh, mm; split2(tv, hh, mm); th[j] = hh; tm[j] = mm;
        }
        *(f16x4*)(Th + mo) = th;
        *(f16x4*)(Tm + mo) = tm;
    } else {
        v = *(const f32x4*)(inp0 + (size_t)b * inp_stride + c);
    }
    size_t o = ((size_t)r << 10) + c;
    *(f32x4*)(mbuf + o) = v;
    f16x4 h, m;
    #pragma unroll
    for (int j = 0; j < 4; j++) { _Float16 hh, mm; split2(v[j], hh, mm); h[j] = hh; m[j] = mm; }
    *(f16x4*)(Ph + o) = h;
    *(f16x4*)(Pm + o) = m;
}

// =====================================================================
// fp16 split-2 (3-term) MFMA GEMM, double-buffered LDS, 1 barrier/k-step.
// C(MxN) = A * B^T + bias. A planes [M][1024], B planes [N][1024] fp16.
// 128x128 tile, BK=32, 256 thr (4 waves 2x2), K = 1024 fixed.
// =====================================================================
template <int RELU, int WF32, int WPL>
__global__ __launch_bounds__(256) void k_gemm2(
    const _Float16* __restrict__ APh, const _Float16* __restrict__ APm,
    const _Float16* __restrict__ BPh, const _Float16* __restrict__ BPm,
    const float* __restrict__ bias,
    float* __restrict__ C, long ldc,
    _Float16* __restrict__ Ph, _Float16* __restrict__ Pm) {
    __shared__ __align__(16) char smem[65536];  // 2 bufs x 32KB (Ah|Am|Bh|Bm 8KB each)
    const int row0 = blockIdx.x * 128;
    const int col0 = blockIdx.y * 128;
    const int tid  = threadIdx.x;
    const int l    = tid & 63;
    const int w    = tid >> 6;
    const int wr   = w >> 1, wc = w & 1;

    f32x4 acc[4][4] = {};

    // staging addresses (per lane): row w*32+(l>>2), swizzled 16B chunk
    const int r_l = w * 32 + (l >> 2);
    const int kc  = (l & 3) ^ ((l >> 3) & 3);
    const _Float16* aH = APh + (size_t)(row0 + r_l) * 1024 + kc * 8;
    const _Float16* aM = APm + (size_t)(row0 + r_l) * 1024 + kc * 8;
    const _Float16* bH = BPh + (size_t)(col0 + r_l) * 1024 + kc * 8;
    const _Float16* bM = BPm + (size_t)(col0 + r_l) * 1024 + kc * 8;

    // frag read offsets (swizzle-matched)
    const int kcsel = l >> 4, rsel = l & 15;
    const int swz   = (kcsel ^ ((rsel >> 1) & 3)) * 16;
    const int offA  = (wr * 64 + rsel) * 64 + swz;
    const int offB  = (wc * 64 + rsel) * 64 + swz;

#define STAGE_T(buf, kk) do {                                  \
        char* dst = smem + (buf) * 32768 + w * 2048;           \
        gload_lds16(aH + (kk),         dst);                   \
        gload_lds16(aH + (kk) + 16384, dst + 1024);            \
        gload_lds16(aM + (kk),         dst + 8192);            \
        gload_lds16(aM + (kk) + 16384, dst + 9216);            \
        gload_lds16(bH + (kk),         dst + 16384);           \
        gload_lds16(bH + (kk) + 16384, dst + 17408);           \
        gload_lds16(bM + (kk),         dst + 24576);           \
        gload_lds16(bM + (kk) + 16384, dst + 25600);           \
    } while (0)

#define COMPUTE_T(buf) do {                                                     \
        const char* sb = smem + (buf) * 32768;                                  \
        f16x8 ah[4], am[4], bh[4], bm[4];                                       \
        _Pragma("unroll")                                                       \
        for (int mm = 0; mm < 4; mm++) {                                        \
            ah[mm] = *(const f16x8*)(sb + offA + mm * 1024);                    \
            am[mm] = *(const f16x8*)(sb + 8192 + offA + mm * 1024);             \
        }                                                                       \
        _Pragma("unroll")                                                       \
        for (int nn = 0; nn < 4; nn++) {                                        \
            bh[nn] = *(const f16x8*)(sb + 16384 + offB + nn * 1024);            \
            bm[nn] = *(const f16x8*)(sb + 24576 + offB + nn * 1024);            \
        }                                                                       \
        _Pragma("unroll")                                                       \
        for (int mm = 0; mm < 4; mm++) {                                        \
            _Pragma("unroll")                                                   \
            for (int nn = 0; nn < 4; nn++) {                                    \
                f32x4 cc = acc[mm][nn];                                         \
                cc = __builtin_amdgcn_mfma_f32_16x16x32_f16(am[mm], bh[nn], cc, 0, 0, 0); \
                cc = __builtin_amdgcn_mfma_f32_16x16x32_f16(ah[mm], bm[nn], cc, 0, 0, 0); \
                cc = __builtin_amdgcn_mfma_f32_16x16x32_f16(ah[mm], bh[nn], cc, 0, 0, 0); \
                acc[mm][nn] = cc;                                               \
            }                                                                   \
        }                                                                       \
    } while (0)

    STAGE_T(0, 0);
    __syncthreads();
    int cur = 0;
    #pragma unroll 1
    for (int ks = 0; ks < 31; ks++) {
        STAGE_T(cur ^ 1, (ks + 1) * 32);
        COMPUTE_T(cur);
        __syncthreads();   // drains vmcnt(0) (prefetch) + protects LDS reuse
        cur ^= 1;
    }
    COMPUTE_T(cur);
#undef STAGE_T
#undef COMPUTE_T

    const int r_in = (l >> 4) * 4;
    const int c_in = l & 15;
    #pragma unroll
    for (int mm = 0; mm < 4; mm++) {
        #pragma unroll
        for (int nn = 0; nn < 4; nn++) {
            int col = col0 + wc * 64 + nn * 16 + c_in;
            float bv = bias[col];
            #pragma unroll
            for (int j = 0; j < 4; j++) {
                int row = row0 + wr * 64 + mm * 16 + r_in + j;
                float v = acc[mm][nn][j] + bv;
                if (RELU) v = fmaxf(v, 0.f);
                size_t o = (size_t)row * ldc + col;
                if (WF32) C[o] = v;
                if (WPL) {
                    _Float16 h, m; split2(v, h, m);
                    Ph[o] = h; Pm[o] = m;
                }
            }
        }
    }
}

// =====================================================================
// FUSED: LN(qkv) + attention + m = LN(m + att) + emit planes.
// grid = BATCH, 512 threads. qkv is RAW (pre-LN) [B*9][3072].
// =====================================================================
__global__ __launch_bounds__(512) void k_ln_attn_addln1(
    const float* __restrict__ qkv,
    const float* __restrict__ gq, const float* __restrict__ bq,   // [9][3072]
    float* __restrict__ mbuf,                                     // [B*9][1024]
    _Float16* __restrict__ Ph, _Float16* __restrict__ Pm,
    const float* __restrict__ g1, const float* __restrict__ b1) { // [9216]
    __shared__ float att_out[9][1024];
    __shared__ float qs[9][128], ks[9][128], vs[9][128];
    __shared__ float att[9][12];
    __shared__ float red[16];
    const int tid = threadIdx.x;
    const int b   = blockIdx.x;
    const float* Q = qkv + (size_t)b * 9 * 3072;

    // ---- pass 1: LN stats over raw qkv (27648 elems) ----
    float s = 0.f, ss = 0.f;
    for (int i = tid * 4; i < 27648; i += 2048) {
        f32x4 v = *(const f32x4*)(Q + i);
        s  += v[0] + v[1] + v[2] + v[3];
        ss += v[0]*v[0] + v[1]*v[1] + v[2]*v[2] + v[3]*v[3];
    }
    bred8(s, ss, red, tid);
    const float invn = 1.f / 27648.f;
    const float mean = s * invn;
    const float rstd = rsqrtf(ss * invn - mean * mean + 1e-5f);

    // ---- attention, heads sequential (normalize on the fly) ----
    const float scale = 0.08838834764831845f;  // 128^-0.5
    for (int h = 0; h < 8; h++) {
        __syncthreads();
        for (int i = tid; i < 1152; i += 512) {
            int sx = i >> 7, d = i & 127;
            int gb = sx * 3072 + h * 384;
            float qv = (Q[gb + d]       - mean) * rstd;
            float kv = (Q[gb + 128 + d] - mean) * rstd;
            float vv = (Q[gb + 256 + d] - mean) * rstd;
            qs[sx][d] = (qv * gq[gb + d]       + bq[gb + d]) * scale;
            ks[sx][d] =  kv * gq[gb + 128 + d] + bq[gb + 128 + d];
            vs[sx][d] =  vv * gq[gb + 256 + d] + bq[gb + 256 + d];
        }
        __syncthreads();
        if (tid < 81) {
            int qi = tid / 9, ki = tid - qi * 9;
            float d = 0.f;
            #pragma unroll 8
            for (int c = 0; c < 128; c++) d += qs[qi][c] * ks[ki][c];
            att[qi][ki] = d;
        }
        __syncthreads();
        if (tid < 9) {
            float mx = att[tid][0];
            #pragma unroll
            for (int j = 1; j < 9; j++) mx = fmaxf(mx, att[tid][j]);
            float e[9]; float sum = 0.f;
            #pragma unroll
            for (int j = 0; j < 9; j++) { e[j] = expf(att[tid][j] - mx); sum += e[j]; }
            float inv = 1.f / sum;
            #pragma unroll
            for (int j = 0; j < 9; j++) att[tid][j] = e[j] * inv;
        }
        __syncthreads();
        for (int i = tid; i < 1152; i += 512) {
            int sx = i >> 7, d = i & 127;
            float ov = 0.f;
            #pragma unroll
            for (int k = 0; k < 9; k++) ov += att[sx][k] * vs[k][d];
            att_out[sx][h * 128 + d] = ov;
        }
    }
    __syncthreads();

    // ---- m = LN(m + att_out), emit f32 + planes ----
    float* X = &att_out[0][0];
    float* M = mbuf + (size_t)b * 9216;
    s = 0.f; ss = 0.f;
    for (int i = tid * 4; i < 9216; i += 2048) {
        f32x4 v = *(const f32x4*)(M + i) + *(const f32x4*)(X + i);
        *(f32x4*)(X + i) = v;
        s  += v[0] + v[1] + v[2] + v[3];
        ss += v[0]*v[0] + v[1]*v[1] + v[2]*v[2] + v[3]*v[3];
    }
    bred8(s, ss, red, tid);
    const float invn2 = 1.f / 9216.f;
    const float mean2 = s * invn2;
    const float rstd2 = rsqrtf(ss * invn2 - mean2 * mean2 + 1e-5f);
    for (int i = tid * 4; i < 9216; i += 2048) {
        f32x4 v  = *(const f32x4*)(X + i);
        f32x4 gg = *(const f32x4*)(g1 + i);
        f32x4 bv = *(const f32x4*)(b1 + i);
        v = (v - mean2) * rstd2 * gg + bv;
        *(f32x4*)(M + i) = v;
        f16x4 h, m;
        #pragma unroll
        for (int j = 0; j < 4; j++) { _Float16 hh, mm; split2(v[j], hh, mm); h[j] = hh; m[j] = mm; }
        size_t oo = (size_t)b * 9216 + i;
        *(f16x4*)(Ph + oo) = h;
        *(f16x4*)(Pm + oo) = m;
    }
}

// =====================================================================
// FUSED: m = LN(m + h2); gate; write out_t, mem, next-step mbuf(+planes),
// tanh planes. grid = BATCH, 512 threads.
// =====================================================================
__global__ __launch_bounds__(512) void k_addln2_gate(
    float* __restrict__ mbuf, const float* __restrict__ h2,
    const float* __restrict__ g2, const float* __restrict__ b2,  // [9216]
    const float* __restrict__ gmem,                              // [B*8][2048]
    const float* __restrict__ ginp, long ginp_stride,
    const float* __restrict__ inp_next, long inp_stride,         // may be null
    const float* __restrict__ fbp, const float* __restrict__ ibp,
    float* __restrict__ mem, float* __restrict__ outp,
    _Float16* __restrict__ Ph, _Float16* __restrict__ Pm,
    _Float16* __restrict__ Th, _Float16* __restrict__ Tm) {
    __shared__ float xs[9216];
    __shared__ float red[16];
    const int tid = threadIdx.x, b = blockIdx.x;
    float* M = mbuf + (size_t)b * 9216;
    const float* H = h2 + (size_t)b * 9216;
    float s = 0.f, ss = 0.f;
    for (int i = tid * 4; i < 9216; i += 2048) {
        f32x4 v = *(const f32x4*)(M + i) + *(const f32x4*)(H + i);
        *(f32x4*)(xs + i) = v;
        s  += v[0] + v[1] + v[2] + v[3];
        ss += v[0]*v[0] + v[1]*v[1] + v[2]*v[2] + v[3]*v[3];
    }
    bred8(s, ss, red, tid);
    const float invn = 1.f / 9216.f;
    const float mean = s * invn;
    const float rstd = rsqrtf(ss * invn - mean * mean + 1e-5f);
    const float FB = *fbp, IB = *ibp;

    for (int i = tid * 4; i < 8192; i += 2048) {
        int sx = i >> 10, c = i & 1023;
        size_t gr = (size_t)(b * 8 + sx);
        f32x4 x   = *(const f32x4*)(xs + i);
        f32x4 gm1 = *(const f32x4*)(gmem + gr * 2048 + c);
        f32x4 gm2 = *(const f32x4*)(gmem + gr * 2048 + 1024 + c);
        f32x4 gi1 = *(const f32x4*)(ginp + (size_t)b * ginp_stride + c);
        f32x4 gi2 = *(const f32x4*)(ginp + (size_t)b * ginp_stride + 1024 + c);
        f32x4 old = *(const f32x4*)(mem + gr * 1024 + c);
        f32x4 gg  = *(const f32x4*)(g2 + i);
        f32x4 bb  = *(const f32x4*)(b2 + i);
        f32x4 o;
        f16x4 oh, om, th, tm;
        #pragma unroll
        for (int j = 0; j < 4; j++) {
            float cand = (x[j] - mean) * rstd * gg[j] + bb[j];
            float igv = sigf(gm1[j] + gi1[j] + IB);
            float fgv = sigf(gm2[j] + gi2[j] + FB);
            o[j] = igv * tanhf(cand) + fgv * old[j];
            _Float16 hh, mm; split2(o[j], hh, mm); oh[j] = hh; om[j] = mm;
            float tv = tanhf(o[j]);
            split2(tv, hh, mm); th[j] = hh; tm[j] = mm;
        }
        *(f32x4*)(mem + gr * 1024 + c)       = o;
        *(f32x4*)(outp + (size_t)b * 8192 + i) = o;
        *(f32x4*)(M + i)                     = o;
        size_t oo = (size_t)b * 9216 + i;
        *(f16x4*)(Ph + oo) = oh;
        *(f16x4*)(Pm + oo) = om;
        size_t to = (size_t)b * 8192 + i;
        *(f16x4*)(Th + to) = th;
        *(f16x4*)(Tm + to) = tm;
    }
    // row 8 of next-step mbuf = inp_{t+1}
    if (inp_next != nullptr && tid < 256) {
        int c = tid * 4;
        f32x4 v = *(const f32x4*)(inp_next + (size_t)b * inp_stride + c);
        *(f32x4*)(M + 8192 + c) = v;
        f16x4 h, m;
        #pragma unroll
        for (int j = 0; j < 4; j++) { _Float16 hh, mm; split2(v[j], hh, mm); h[j] = hh; m[j] = mm; }
        size_t oo = (size_t)b * 9216 + 8192 + c;
        *(f16x4*)(Ph + oo) = h;
        *(f16x4*)(Pm + oo) = m;
    }
}

// =====================================================================
// host launcher
// =====================================================================
extern "C" void kernel_launch(void* const* d_in, const int* in_sizes, int n_in,
                              void* d_out, int out_size, void* d_ws, size_t ws_size,
                              hipStream_t stream) {
    const float* inputs = (const float*)d_in[0];
    const float* memory = (const float*)d_in[1];
    const float* W_qkv  = (const float*)d_in[2];
    const float* b_qkv  = (const float*)d_in[3];
    const float* g_qln  = (const float*)d_in[4];
    const float* b_qln  = (const float*)d_in[5];
    const float* W_mlp  = (const float*)d_in[6];
    const float* b_mlp  = (const float*)d_in[7];
    const float* g_ln1  = (const float*)d_in[8];
    const float* b_ln1  = (const float*)d_in[9];
    const float* g_ln2  = (const float*)d_in[10];
    const float* b_ln2  = (const float*)d_in[11];
    const float* W_in   = (const float*)d_in[12];
    const float* b_in   = (const float*)d_in[13];
    const float* W_ig   = (const float*)d_in[14];
    const float* b_ig   = (const float*)d_in[15];
    const float* W_mg   = (const float*)d_in[16];
    const float* b_mg   = (const float*)d_in[17];
    const float* fb     = (const float*)d_in[18];
    const float* ib     = (const float*)d_in[19];
    float* out = (float*)d_out;

    char* ws = (char*)d_ws;
    size_t off = 0;
    auto alloc = [&](size_t bytes) -> char* {
        char* p = ws + off;
        off += (bytes + 255) & ~(size_t)255;
        return p;
    };
    const size_t NEin = (size_t)1024*1024, NEqkv = (size_t)3072*1024,
                 NEmlp = (size_t)1024*1024, NEig = (size_t)2048*1024, NEmg = (size_t)2048*1024;
    _Float16* WinP  = (_Float16*)alloc(NEin  * 2 * 2);
    _Float16* WqkvP = (_Float16*)alloc(NEqkv * 2 * 2);
    _Float16* WmlpP = (_Float16*)alloc(NEmlp * 2 * 2);
    _Float16* WigP  = (_Float16*)alloc(NEig  * 2 * 2);
    _Float16* WmgP  = (_Float16*)alloc(NEmg  * 2 * 2);

    float*    mem_ws = (float*)alloc((size_t)2048 * 1024 * 4);
    float*    mbuf   = (float*)alloc((size_t)2304 * 1024 * 4);
    _Float16* mbufP  = (_Float16*)alloc((size_t)2304 * 1024 * 2 * 2);
    float*    qkvbuf = (float*)alloc((size_t)2304 * 3072 * 4);
    _Float16* h1P    = (_Float16*)alloc((size_t)2304 * 1024 * 2 * 2);
    float*    h2buf  = (float*)alloc((size_t)2304 * 1024 * 4);
    _Float16* tanhP  = (_Float16*)alloc((size_t)2048 * 1024 * 2 * 2);
    float*    gmem   = qkvbuf;  // alias: qkv dead after ln_attn

    const size_t NEm   = (size_t)2304 * 1024;
    const size_t NEt   = (size_t)2048 * 1024;
    const size_t NEbig = (size_t)8192 * 1024;

    size_t big_bytes = NEbig*2*2 + NEbig*4 + NEbig*2*2 + (size_t)8192*2048*4 + 8192;
    bool big = (ws_size >= off + big_bytes);

    dim3 tb(32, 8);
    k_transpose_split2<<<dim3(32, 32), tb, 0, stream>>>(W_in,  WinP,  WinP + NEin,  1024, 1024);
    k_transpose_split2<<<dim3(32, 96), tb, 0, stream>>>(W_qkv, WqkvP, WqkvP + NEqkv, 3072, 1024);
    k_transpose_split2<<<dim3(32, 32), tb, 0, stream>>>(W_mlp, WmlpP, WmlpP + NEmlp, 1024, 1024);
    k_transpose_split2<<<dim3(32, 64), tb, 0, stream>>>(W_ig,  WigP,  WigP + NEig,  2048, 1024);
    k_transpose_split2<<<dim3(32, 64), tb, 0, stream>>>(W_mg,  WmgP,  WmgP + NEmg,  2048, 1024);

    if (big) {
        _Float16* inputsP  = (_Float16*)alloc(NEbig * 2 * 2);
        float*    inp_all  = (float*)alloc(NEbig * 4);
        _Float16* inp_allP = (_Float16*)alloc(NEbig * 2 * 2);
        float*    ginp_all = (float*)alloc((size_t)8192 * 2048 * 4);

        k_split2_rows<<<8192, 256, 0, stream>>>(inputs, 1024, inputsP, inputsP + NEbig, 8192 * 256);
        k_gemm2<0,1,1><<<dim3(64, 8), 256, 0, stream>>>(inputsP, inputsP + NEbig,
            WinP, WinP + NEin, b_in, inp_all, 1024, inp_allP, inp_allP + NEbig);
        k_gemm2<0,1,0><<<dim3(64, 16), 256, 0, stream>>>(inp_allP, inp_allP + NEbig,
            WigP, WigP + NEig, b_ig, ginp_all, 2048, nullptr, nullptr);
        k_prep0<<<2304, 256, 0, stream>>>(mbuf, mbufP, mbufP + NEm, memory, mem_ws,
                                          tanhP, tanhP + NEt, inp_all, (long)SEQT * 1024);

        for (int t = 0; t < SEQT; t++) {
            k_gemm2<0,1,0><<<dim3(18, 24), 256, 0, stream>>>(mbufP, mbufP + NEm,
                WqkvP, WqkvP + NEqkv, b_qkv, qkvbuf, 3072, nullptr, nullptr);
            k_ln_attn_addln1<<<BATCH, 512, 0, stream>>>(qkvbuf, g_qln, b_qln,
                mbuf, mbufP, mbufP + NEm, g_ln1, b_ln1);
            k_gemm2<1,0,1><<<dim3(18, 8), 256, 0, stream>>>(mbufP, mbufP + NEm,
                WmlpP, WmlpP + NEmlp, b_mlp, nullptr, 1024, h1P, h1P + NEm);
            k_gemm2<1,1,0><<<dim3(18, 8), 256, 0, stream>>>(h1P, h1P + NEm,
                WmlpP, WmlpP + NEmlp, b_mlp, h2buf, 1024, nullptr, nullptr);
            k_gemm2<0,1,0><<<dim3(16, 16), 256, 0, stream>>>(tanhP, tanhP + NEt,
                WmgP, WmgP + NEmg, b_mg, gmem, 2048, nullptr, nullptr);
            const float* inp_next = (t + 1 < SEQT) ? (inp_all + (size_t)(t + 1) * 1024) : nullptr;
            k_addln2_gate<<<BATCH, 512, 0, stream>>>(mbuf, h2buf, g_ln2, b_ln2,
                gmem, ginp_all + (size_t)t * 2048, (long)SEQT * 2048,
                inp_next, (long)SEQT * 1024, fb, ib, mem_ws,
                out + (size_t)t * (BATCH * 8192),
                mbufP, mbufP + NEm, tanhP, tanhP + NEt);
        }
    } else {
        // small-ws fallback: per-step input projections (double-buffered)
        const size_t NEs = (size_t)256 * 1024;
        _Float16* stepP  = (_Float16*)alloc(NEs * 2 * 2);
        float*    inpA   = (float*)alloc(NEs * 4);
        _Float16* inpAP  = (_Float16*)alloc(NEs * 2 * 2);
        float*    inpB   = (float*)alloc(NEs * 4);
        _Float16* inpBP  = (_Float16*)alloc(NEs * 2 * 2);
        float*    ginpA  = (float*)alloc((size_t)256 * 2048 * 4);
        float*    ginpB  = (float*)alloc((size_t)256 * 2048 * 4);

        k_split2_rows<<<256, 256, 0, stream>>>(inputs, (long)SEQT * 1024, stepP, stepP + NEs, 256 * 256);
        k_gemm2<0,1,1><<<dim3(2, 8), 256, 0, stream>>>(stepP, stepP + NEs,
            WinP, WinP + NEin, b_in, inpA, 1024, inpAP, inpAP + NEs);
        k_gemm2<0,1,0><<<dim3(2, 16), 256, 0, stream>>>(inpAP, inpAP + NEs,
            WigP, WigP + NEig, b_ig, ginpA, 2048, nullptr, nullptr);
        k_prep0<<<2304, 256, 0, stream>>>(mbuf, mbufP, mbufP + NEm, memory, mem_ws,
                                          tanhP, tanhP + NEt, inpA, 1024);

        float *ci = inpA, *cg = ginpA, *ni = inpB, *ng = ginpB;
        _Float16* niP = inpBP;
        _Float16* ciP = inpAP;
        for (int t = 0; t < SEQT; t++) {
            k_gemm2<0,1,0><<<dim3(18, 24), 256, 0, stream>>>(mbufP, mbufP + NEm,
                WqkvP, WqkvP + NEqkv, b_qkv, qkvbuf, 3072, nullptr, nullptr);
            k_ln_attn_addln1<<<BATCH, 512, 0, stream>>>(qkvbuf, g_qln, b_qln,
                mbuf, mbufP, mbufP + NEm, g_ln1, b_ln1);
            k_gemm2<1,0,1><<<dim3(18, 8), 256, 0, stream>>>(mbufP, mbufP + NEm,
                WmlpP, WmlpP + NEmlp, b_mlp, nullptr, 1024, h1P, h1P + NEm);
            k_gemm2<1,1,0><<<dim3(18, 8), 256, 0, stream>>>(h1P, h1P + NEm,
                WmlpP, WmlpP + NEmlp, b_mlp, h2buf, 1024, nullptr, nullptr);
            k_gemm2<0,1,0><<<dim3(16, 16), 256, 0, stream>>>(tanhP, tanhP + NEt,
                WmgP, WmgP + NEmg, b_mg, gmem, 2048, nullptr, nullptr);
            const float* inp_next = nullptr;
            if (t + 1 < SEQT) {
                k_split2_rows<<<256, 256, 0, stream>>>(inputs + (size_t)(t + 1) * 1024,
                    (long)SEQT * 1024, stepP, stepP + NEs, 256 * 256);
                k_gemm2<0,1,1><<<dim3(2, 8), 256, 0, stream>>>(stepP, stepP + NEs,
                    WinP, WinP + NEin, b_in, ni, 1024, niP, niP + NEs);
                k_gemm2<0,1,0><<<dim3(2, 16), 256, 0, stream>>>(niP, niP + NEs,
                    WigP, WigP + NEig, b_ig, ng, 2048, nullptr, nullptr);
                inp_next = ni;
            }
            k_addln2_gate<<<BATCH, 512, 0, stream>>>(mbuf, h2buf, g_ln2, b_ln2,
                gmem, cg, 2048, inp_next, 1024, fb, ib, mem_ws,
                out + (size_t)t * (BATCH * 8192),
                mbufP, mbufP + NEm, tanhP, tanhP + NEt);
            { float* tmp = ci; ci = ni; ni = tmp; }
            { float* tmp = cg; cg = ng; ng = tmp; }
            { _Float16* tmp = ciP; ciP = niP; niP = tmp; }
        }
    }
    k_copy<<<2048, 256, 0, stream>>>(mem_ws, out + (size_t)SEQT * BATCH * 8192, 524288);
}

// Round 5
// 6447.499 us; speedup vs baseline: 1.9506x; 1.0621x over previous
//
#include <hip/hip_runtime.h>
#include <hip/hip_bf16.h>
#include <cstdint>
#include <cstddef>

// ---------------- types ----------------
typedef float    f32x4 __attribute__((ext_vector_type(4)));
typedef _Float16 f16x8 __attribute__((ext_vector_type(8)));
typedef _Float16 f16x4 __attribute__((ext_vector_type(4)));

#define BATCH 256
#define SEQT  32
#define S1    9

__device__ __forceinline__ void split2(float a, _Float16& h, _Float16& m) {
    h = (_Float16)a;
    m = (_Float16)(a - (float)h);
}
__device__ __forceinline__ float sigf(float x) { return 1.f / (1.f + expf(-x)); }

__device__ __forceinline__ void gload_lds16(const void* g, void* l) {
    __builtin_amdgcn_global_load_lds(
        (const __attribute__((address_space(1))) unsigned int*)g,
        (__attribute__((address_space(3))) unsigned int*)l, 16, 0, 0);
}

// block-wide (8 waves, 512 thr) sum of (s, ss)
__device__ __forceinline__ void bred8(float& s, float& ss, float* red, int tid) {
    #pragma unroll
    for (int o = 32; o > 0; o >>= 1) {
        s  += __shfl_down(s,  o, 64);
        ss += __shfl_down(ss, o, 64);
    }
    __syncthreads();
    if ((tid & 63) == 0) { red[(tid >> 6) * 2] = s; red[(tid >> 6) * 2 + 1] = ss; }
    __syncthreads();
    s = 0.f; ss = 0.f;
    #pragma unroll
    for (int wv = 0; wv < 8; wv++) { s += red[wv * 2]; ss += red[wv * 2 + 1]; }
}

// =====================================================================
// Weight transpose + 2-way fp16 split: W (K x N) f32 -> H/M (N x K) fp16
// =====================================================================
__global__ void k_transpose_split2(const float* __restrict__ W,
                                   _Float16* __restrict__ H, _Float16* __restrict__ M,
                                   int N, int K) {
    __shared__ float tile[32][33];
    int k0 = blockIdx.x * 32, n0 = blockIdx.y * 32;
    int tx = threadIdx.x, ty = threadIdx.y;
    #pragma unroll
    for (int i = ty; i < 32; i += 8)
        tile[i][tx] = W[(size_t)(k0 + i) * N + (n0 + tx)];
    __syncthreads();
    #pragma unroll
    for (int i = ty; i < 32; i += 8) {
        float a = tile[tx][i];
        _Float16 h, m; split2(a, h, m);
        size_t idx = (size_t)(n0 + i) * K + (k0 + tx);
        H[idx] = h; M[idx] = m;
    }
}

// =====================================================================
// split rows of f32 matrix (row stride s_in) into fp16 planes [R][1024]
// =====================================================================
__global__ void k_split2_rows(const float* __restrict__ src, long s_in,
                              _Float16* __restrict__ H, _Float16* __restrict__ M,
                              int n4) {
    int i = blockIdx.x * 256 + threadIdx.x;
    if (i >= n4) return;
    int e = i << 2;
    int c = e & 1023;
    int r = e >> 10;
    f32x4 v = *(const f32x4*)(src + (size_t)r * s_in + c);
    f16x4 h, m;
    #pragma unroll
    for (int j = 0; j < 4; j++) { _Float16 hh, mm; split2(v[j], hh, mm); h[j] = hh; m[j] = mm; }
    size_t o = ((size_t)r << 10) + c;
    *(f16x4*)(H + o) = h;
    *(f16x4*)(M + o) = m;
}

__global__ void k_copy(const float* __restrict__ src, float* __restrict__ dst, int n4) {
    int i = blockIdx.x * 256 + threadIdx.x;
    if (i < n4) ((f32x4*)dst)[i] = ((const f32x4*)src)[i];
}

// =====================================================================
// step-0 prep: mbuf = concat(memory, inp0) (f32 + planes), mem_ws copy,
// tanh planes of memory. grid 2304 x 256 (vec4)
// =====================================================================
__global__ void k_prep0(float* __restrict__ mbuf,
                        _Float16* __restrict__ Ph, _Float16* __restrict__ Pm,
                        const float* __restrict__ memory, float* __restrict__ mem_ws,
                        _Float16* __restrict__ Th, _Float16* __restrict__ Tm,
                        const float* __restrict__ inp0, long inp_stride) {
    int i = blockIdx.x * 256 + threadIdx.x;
    int e = i << 2;
    int c = e & 1023;
    int r = e >> 10;
    int b = r / 9, s = r - b * 9;
    f32x4 v;
    if (s < 8) {
        size_t mo = (((size_t)(b * 8 + s)) << 10) + c;
        v = *(const f32x4*)(memory + mo);
        *(f32x4*)(mem_ws + mo) = v;
        f16x4 th, tm;
        #pragma unroll
        for (int j = 0; j < 4; j++) {
            float tv = tanhf(v[j]);
            _Float16 hh, mm; split2(tv, hh, mm); th[j] = hh; tm[j] = mm;
        }
        *(f16x4*)(Th + mo) = th;
        *(f16x4*)(Tm + mo) = tm;
    } else {
        v = *(const f32x4*)(inp0 + (size_t)b * inp_stride + c);
    }
    size_t o = ((size_t)r << 10) + c;
    *(f32x4*)(mbuf + o) = v;
    f16x4 h, m;
    #pragma unroll
    for (int j = 0; j < 4; j++) { _Float16 hh, mm; split2(v[j], hh, mm); h[j] = hh; m[j] = mm; }
    *(f16x4*)(Ph + o) = h;
    *(f16x4*)(Pm + o) = m;
}

// =====================================================================
// fp16 split-2 (3-term) MFMA GEMM core, double-buffered LDS.
// C(MxN) = A * B^T + bias. A planes [M][1024], B planes [N][1024] fp16.
// BM x 128 tile, BK=32, 256 thr (4 waves 2x2), K = 1024 fixed.
// =====================================================================
template <int BM, int RELU, int WF32, int WPL>
__device__ __forceinline__ void gemm_core(
    const _Float16* __restrict__ APh, const _Float16* __restrict__ APm,
    const _Float16* __restrict__ BPh, const _Float16* __restrict__ BPm,
    const float* __restrict__ bias,
    float* __restrict__ C, long ldc,
    _Float16* __restrict__ Ph, _Float16* __restrict__ Pm,
    int row0, int col0, char* smem) {
    constexpr int ASLAB = BM * 64;              // bytes per A plane (BM rows x 32k x 2B)
    constexpr int BUF   = 2 * ASLAB + 16384;    // Ah|Am|Bh(8K)|Bm(8K)
    constexpr int MM    = BM / 32;              // frag-rows per wave (4 or 2)
    const int tid = threadIdx.x;
    const int l   = tid & 63;
    const int w   = tid >> 6;
    const int wr  = w >> 1, wc = w & 1;

    f32x4 acc[MM][4] = {};

    const int kc = (l & 3) ^ ((l >> 3) & 3);   // inverse-swizzled source chunk
    const int rA = (BM == 128) ? (w * 32 + (l >> 2)) : (w * 16 + (l >> 2));
    const int rB = w * 32 + (l >> 2);
    const _Float16* aH = APh + (size_t)(row0 + rA) * 1024 + kc * 8;
    const _Float16* aM = APm + (size_t)(row0 + rA) * 1024 + kc * 8;
    const _Float16* bH = BPh + (size_t)(col0 + rB) * 1024 + kc * 8;
    const _Float16* bM = BPm + (size_t)(col0 + rB) * 1024 + kc * 8;

    const int kcsel = l >> 4, rsel = l & 15;
    const int swz  = (kcsel ^ ((rsel >> 1) & 3)) * 16;
    const int offA = (wr * (BM / 2) + rsel) * 64 + swz;
    const int offB = (wc * 64 + rsel) * 64 + swz;

#define STG(buf, kk) do {                                        \
        char* dst = smem + (buf) * BUF;                          \
        if (BM == 128) {                                         \
            char* da = dst + w * 2048;                           \
            gload_lds16(aH + (kk),         da);                  \
            gload_lds16(aH + (kk) + 16384, da + 1024);           \
            gload_lds16(aM + (kk),         da + ASLAB);          \
            gload_lds16(aM + (kk) + 16384, da + ASLAB + 1024);   \
        } else {                                                 \
            char* da = dst + w * 1024;                           \
            gload_lds16(aH + (kk), da);                          \
            gload_lds16(aM + (kk), da + ASLAB);                  \
        }                                                        \
        char* db = dst + 2 * ASLAB + w * 2048;                   \
        gload_lds16(bH + (kk),         db);                      \
        gload_lds16(bH + (kk) + 16384, db + 1024);               \
        gload_lds16(bM + (kk),         db + 8192);               \
        gload_lds16(bM + (kk) + 16384, db + 9216);               \
    } while (0)

#define CMP(buf) do {                                                           \
        const char* sb = smem + (buf) * BUF;                                    \
        f16x8 ah[MM], am[MM], bh[4], bm[4];                                     \
        _Pragma("unroll")                                                       \
        for (int mm = 0; mm < MM; mm++) {                                       \
            ah[mm] = *(const f16x8*)(sb + offA + mm * 1024);                    \
            am[mm] = *(const f16x8*)(sb + ASLAB + offA + mm * 1024);            \
        }                                                                       \
        _Pragma("unroll")                                                       \
        for (int nn = 0; nn < 4; nn++) {                                        \
            bh[nn] = *(const f16x8*)(sb + 2 * ASLAB + offB + nn * 1024);        \
            bm[nn] = *(const f16x8*)(sb + 2 * ASLAB + 8192 + offB + nn * 1024); \
        }                                                                       \
        _Pragma("unroll")                                                       \
        for (int mm = 0; mm < MM; mm++) {                                       \
            _Pragma("unroll")                                                   \
            for (int nn = 0; nn < 4; nn++) {                                    \
                f32x4 cc = acc[mm][nn];                                         \
                cc = __builtin_amdgcn_mfma_f32_16x16x32_f16(am[mm], bh[nn], cc, 0, 0, 0); \
                cc = __builtin_amdgcn_mfma_f32_16x16x32_f16(ah[mm], bm[nn], cc, 0, 0, 0); \
                cc = __builtin_amdgcn_mfma_f32_16x16x32_f16(ah[mm], bh[nn], cc, 0, 0, 0); \
                acc[mm][nn] = cc;                                               \
            }                                                                   \
        }                                                                       \
    } while (0)

    STG(0, 0);
    __syncthreads();
    int cur = 0;
    #pragma unroll 1
    for (int ks = 0; ks < 31; ks++) {
        STG(cur ^ 1, (ks + 1) * 32);
        CMP(cur);
        __syncthreads();
        cur ^= 1;
    }
    CMP(cur);
#undef STG
#undef CMP

    const int r_in = (l >> 4) * 4;
    const int c_in = l & 15;
    #pragma unroll
    for (int mm = 0; mm < MM; mm++) {
        #pragma unroll
        for (int nn = 0; nn < 4; nn++) {
            int col = col0 + wc * 64 + nn * 16 + c_in;
            float bv = bias[col];
            #pragma unroll
            for (int j = 0; j < 4; j++) {
                int row = row0 + wr * (BM / 2) + mm * 16 + r_in + j;
                float v = acc[mm][nn][j] + bv;
                if (RELU) v = fmaxf(v, 0.f);
                size_t o = (size_t)row * ldc + col;
                if (WF32) C[o] = v;
                if (WPL) {
                    _Float16 h, m; split2(v, h, m);
                    Ph[o] = h; Pm[o] = m;
                }
            }
        }
    }
}

// standalone GEMM kernel
template <int BM, int RELU, int WF32, int WPL>
__global__ __launch_bounds__(256) void k_gemm2(
    const _Float16* __restrict__ APh, const _Float16* __restrict__ APm,
    const _Float16* __restrict__ BPh, const _Float16* __restrict__ BPm,
    const float* __restrict__ bias,
    float* __restrict__ C, long ldc,
    _Float16* __restrict__ Ph, _Float16* __restrict__ Pm) {
    __shared__ __align__(16) char smem[(BM * 64 * 2 + 16384) * 2];
    gemm_core<BM, RELU, WF32, WPL>(APh, APm, BPh, BPm, bias, C, ldc, Ph, Pm,
                                   blockIdx.x * BM, blockIdx.y * 128, smem);
}

// grouped pair: two independent 128x128 GEMMs in one dispatch
struct GemmP {
    const _Float16* APh; const _Float16* APm;
    const _Float16* BPh; const _Float16* BPm;
    const float* bias; float* C; long ldc;
};
__global__ __launch_bounds__(256) void k_gemm_pair(GemmP p0, int n0, int gw0,
                                                   GemmP p1, int gw1) {
    __shared__ __align__(16) char smem[65536];
    int id = blockIdx.x;
    if (id < n0) {
        gemm_core<128, 0, 1, 0>(p0.APh, p0.APm, p0.BPh, p0.BPm, p0.bias, p0.C, p0.ldc,
                                nullptr, nullptr, (id % gw0) * 128, (id / gw0) * 128, smem);
    } else {
        id -= n0;
        gemm_core<128, 0, 1, 0>(p1.APh, p1.APm, p1.BPh, p1.BPm, p1.bias, p1.C, p1.ldc,
                                nullptr, nullptr, (id % gw1) * 128, (id / gw1) * 128, smem);
    }
}

// =====================================================================
// FUSED: LN(qkv) + attention (2 heads/iter, wave-parallel QK) +
// m = LN(m + att) + emit planes. grid = BATCH, 512 threads.
// =====================================================================
__global__ __launch_bounds__(512) void k_ln_attn_addln1(
    const float* __restrict__ qkv,
    const float* __restrict__ gq, const float* __restrict__ bq,   // [9][3072]
    float* __restrict__ mbuf,                                     // [B*9][1024]
    _Float16* __restrict__ Ph, _Float16* __restrict__ Pm,
    const float* __restrict__ g1, const float* __restrict__ b1) { // [9216]
    __shared__ float att_out[9][1024];
    __shared__ float qs[2][9][128], ks[2][9][128], vs[2][9][128];
    __shared__ float att[2][9][12];
    __shared__ float red[16];
    const int tid = threadIdx.x;
    const int b   = blockIdx.x;
    const float* Q = qkv + (size_t)b * 9 * 3072;

    // ---- LN stats over raw qkv (27648 elems) ----
    float s = 0.f, ss = 0.f;
    for (int i = tid * 4; i < 27648; i += 2048) {
        f32x4 v = *(const f32x4*)(Q + i);
        s  += v[0] + v[1] + v[2] + v[3];
        ss += v[0]*v[0] + v[1]*v[1] + v[2]*v[2] + v[3]*v[3];
    }
    bred8(s, ss, red, tid);
    const float invn = 1.f / 27648.f;
    const float mean = s * invn;
    const float rstd = rsqrtf(ss * invn - mean * mean + 1e-5f);
    const float scale = 0.08838834764831845f;  // 128^-0.5

    for (int h0 = 0; h0 < 8; h0 += 2) {
        __syncthreads();
        for (int i = tid; i < 2304; i += 512) {
            int hh = i / 1152, rem = i - hh * 1152;
            int sx = rem >> 7, d = rem & 127;
            int gb = sx * 3072 + (h0 + hh) * 384 + d;
            qs[hh][sx][d] = ((Q[gb]       - mean) * rstd * gq[gb]       + bq[gb])       * scale;
            ks[hh][sx][d] =  (Q[gb + 128] - mean) * rstd * gq[gb + 128] + bq[gb + 128];
            vs[hh][sx][d] =  (Q[gb + 256] - mean) * rstd * gq[gb + 256] + bq[gb + 256];
        }
        __syncthreads();
        // QK^T: 162 dots, one per 4-lane group
        for (int g = tid >> 2; g < 162; g += 128) {
            int hh = g / 81, r = g - hh * 81;
            int qi = r / 9, ki = r - qi * 9;
            const float* qp = qs[hh][qi];
            const float* kp = ks[hh][ki];
            float s4 = 0.f;
            for (int d = tid & 3; d < 128; d += 4) s4 += qp[d] * kp[d];
            s4 += __shfl_xor(s4, 1);
            s4 += __shfl_xor(s4, 2);
            if ((tid & 3) == 0) att[hh][qi][ki] = s4;
        }
        __syncthreads();
        if (tid < 18) {
            int hh = tid / 9, qi = tid - hh * 9;
            float mx = att[hh][qi][0];
            #pragma unroll
            for (int j = 1; j < 9; j++) mx = fmaxf(mx, att[hh][qi][j]);
            float e[9]; float sum = 0.f;
            #pragma unroll
            for (int j = 0; j < 9; j++) { e[j] = expf(att[hh][qi][j] - mx); sum += e[j]; }
            float inv = 1.f / sum;
            #pragma unroll
            for (int j = 0; j < 9; j++) att[hh][qi][j] = e[j] * inv;
        }
        __syncthreads();
        for (int i = tid; i < 2304; i += 512) {
            int hh = i / 1152, rem = i - hh * 1152;
            int sx = rem >> 7, d = rem & 127;
            float ov = 0.f;
            #pragma unroll
            for (int k = 0; k < 9; k++) ov += att[hh][sx][k] * vs[hh][k][d];
            att_out[sx][(h0 + hh) * 128 + d] = ov;
        }
    }
    __syncthreads();

    // ---- m = LN(m + att_out), emit f32 + planes ----
    float* X = &att_out[0][0];
    float* M = mbuf + (size_t)b * 9216;
    s = 0.f; ss = 0.f;
    for (int i = tid * 4; i < 9216; i += 2048) {
        f32x4 v = *(const f32x4*)(M + i) + *(const f32x4*)(X + i);
        *(f32x4*)(X + i) = v;
        s  += v[0] + v[1] + v[2] + v[3];
        ss += v[0]*v[0] + v[1]*v[1] + v[2]*v[2] + v[3]*v[3];
    }
    bred8(s, ss, red, tid);
    const float invn2 = 1.f / 9216.f;
    const float mean2 = s * invn2;
    const float rstd2 = rsqrtf(ss * invn2 - mean2 * mean2 + 1e-5f);
    for (int i = tid * 4; i < 9216; i += 2048) {
        f32x4 v  = *(const f32x4*)(X + i);
        f32x4 gg = *(const f32x4*)(g1 + i);
        f32x4 bv = *(const f32x4*)(b1 + i);
        v = (v - mean2) * rstd2 * gg + bv;
        *(f32x4*)(M + i) = v;
        f16x4 h, m;
        #pragma unroll
        for (int j = 0; j < 4; j++) { _Float16 hh, mm; split2(v[j], hh, mm); h[j] = hh; m[j] = mm; }
        size_t oo = (size_t)b * 9216 + i;
        *(f16x4*)(Ph + oo) = h;
        *(f16x4*)(Pm + oo) = m;
    }
}

// =====================================================================
// FUSED: m = LN(m + h2); gate; write out_t, mem, next-step mbuf(+planes),
// tanh planes. grid = BATCH, 512 threads.
// =====================================================================
__global__ __launch_bounds__(512) void k_addln2_gate(
    float* __restrict__ mbuf, const float* __restrict__ h2,
    const float* __restrict__ g2, const float* __restrict__ b2,
    const float* __restrict__ gmem,
    const float* __restrict__ ginp, long ginp_stride,
    const float* __restrict__ inp_next, long inp_stride,
    const float* __restrict__ fbp, const float* __restrict__ ibp,
    float* __restrict__ mem, float* __restrict__ outp,
    _Float16* __restrict__ Ph, _Float16* __restrict__ Pm,
    _Float16* __restrict__ Th, _Float16* __restrict__ Tm) {
    __shared__ float xs[9216];
    __shared__ float red[16];
    const int tid = threadIdx.x, b = blockIdx.x;
    float* M = mbuf + (size_t)b * 9216;
    const float* H = h2 + (size_t)b * 9216;
    float s = 0.f, ss = 0.f;
    for (int i = tid * 4; i < 9216; i += 2048) {
        f32x4 v = *(const f32x4*)(M + i) + *(const f32x4*)(H + i);
        *(f32x4*)(xs + i) = v;
        s  += v[0] + v[1] + v[2] + v[3];
        ss += v[0]*v[0] + v[1]*v[1] + v[2]*v[2] + v[3]*v[3];
    }
    bred8(s, ss, red, tid);
    const float invn = 1.f / 9216.f;
    const float mean = s * invn;
    const float rstd = rsqrtf(ss * invn - mean * mean + 1e-5f);
    const float FB = *fbp, IB = *ibp;

    for (int i = tid * 4; i < 8192; i += 2048) {
        int sx = i >> 10, c = i & 1023;
        size_t gr = (size_t)(b * 8 + sx);
        f32x4 x   = *(const f32x4*)(xs + i);
        f32x4 gm1 = *(const f32x4*)(gmem + gr * 2048 + c);
        f32x4 gm2 = *(const f32x4*)(gmem + gr * 2048 + 1024 + c);
        f32x4 gi1 = *(const f32x4*)(ginp + (size_t)b * ginp_stride + c);
        f32x4 gi2 = *(const f32x4*)(ginp + (size_t)b * ginp_stride + 1024 + c);
        f32x4 old = *(const f32x4*)(mem + gr * 1024 + c);
        f32x4 gg  = *(const f32x4*)(g2 + i);
        f32x4 bb  = *(const f32x4*)(b2 + i);
        f32x4 o;
        f16x4 oh, om, th, tm;
        #pragma unroll
        for (int j = 0; j < 4; j++) {
            float cand = (x[j] - mean) * rstd * gg[j] + bb[j];
            float igv = sigf(gm1[j] + gi1[j] + IB);
            float fgv = sigf(gm2[j] + gi2[j] + FB);
            o[j] = igv * tanhf(cand) + fgv * old[j];
            _Float16 hh, mm; split2(o[j], hh, mm); oh[j] = hh; om[j] = mm;
            float tv = tanhf(o[j]);
            split2(tv, hh, mm); th[j] = hh; tm[j] = mm;
        }
        *(f32x4*)(mem + gr * 1024 + c)         = o;
        *(f32x4*)(outp + (size_t)b * 8192 + i) = o;
        *(f32x4*)(M + i)                       = o;
        size_t oo = (size_t)b * 9216 + i;
        *(f16x4*)(Ph + oo) = oh;
        *(f16x4*)(Pm + oo) = om;
        size_t to = (size_t)b * 8192 + i;
        *(f16x4*)(Th + to) = th;
        *(f16x4*)(Tm + to) = tm;
    }
    if (inp_next != nullptr && tid < 256) {
        int c = tid * 4;
        f32x4 v = *(const f32x4*)(inp_next + (size_t)b * inp_stride + c);
        *(f32x4*)(M + 8192 + c) = v;
        f16x4 h, m;
        #pragma unroll
        for (int j = 0; j < 4; j++) { _Float16 hh, mm; split2(v[j], hh, mm); h[j] = hh; m[j] = mm; }
        size_t oo = (size_t)b * 9216 + 8192 + c;
        *(f16x4*)(Ph + oo) = h;
        *(f16x4*)(Pm + oo) = m;
    }
}

// =====================================================================
// host launcher
// =====================================================================
extern "C" void kernel_launch(void* const* d_in, const int* in_sizes, int n_in,
                              void* d_out, int out_size, void* d_ws, size_t ws_size,
                              hipStream_t stream) {
    const float* inputs = (const float*)d_in[0];
    const float* memory = (const float*)d_in[1];
    const float* W_qkv  = (const float*)d_in[2];
    const float* b_qkv  = (const float*)d_in[3];
    const float* g_qln  = (const float*)d_in[4];
    const float* b_qln  = (const float*)d_in[5];
    const float* W_mlp  = (const float*)d_in[6];
    const float* b_mlp  = (const float*)d_in[7];
    const float* g_ln1  = (const float*)d_in[8];
    const float* b_ln1  = (const float*)d_in[9];
    const float* g_ln2  = (const float*)d_in[10];
    const float* b_ln2  = (const float*)d_in[11];
    const float* W_in   = (const float*)d_in[12];
    const float* b_in   = (const float*)d_in[13];
    const float* W_ig   = (const float*)d_in[14];
    const float* b_ig   = (const float*)d_in[15];
    const float* W_mg   = (const float*)d_in[16];
    const float* b_mg   = (const float*)d_in[17];
    const float* fb     = (const float*)d_in[18];
    const float* ib     = (const float*)d_in[19];
    float* out = (float*)d_out;

    char* ws = (char*)d_ws;
    size_t off = 0;
    auto alloc = [&](size_t bytes) -> char* {
        char* p = ws + off;
        off += (bytes + 255) & ~(size_t)255;
        return p;
    };
    const size_t NEin = (size_t)1024*1024, NEqkv = (size_t)3072*1024,
                 NEmlp = (size_t)1024*1024, NEig = (size_t)2048*1024, NEmg = (size_t)2048*1024;
    _Float16* WinP  = (_Float16*)alloc(NEin  * 2 * 2);
    _Float16* WqkvP = (_Float16*)alloc(NEqkv * 2 * 2);
    _Float16* WmlpP = (_Float16*)alloc(NEmlp * 2 * 2);
    _Float16* WigP  = (_Float16*)alloc(NEig  * 2 * 2);
    _Float16* WmgP  = (_Float16*)alloc(NEmg  * 2 * 2);

    float*    mem_ws = (float*)alloc((size_t)2048 * 1024 * 4);
    float*    mbuf   = (float*)alloc((size_t)2304 * 1024 * 4);
    _Float16* mbufP  = (_Float16*)alloc((size_t)2304 * 1024 * 2 * 2);
    float*    qkvbuf = (float*)alloc((size_t)2304 * 3072 * 4);
    float*    gmemb  = (float*)alloc((size_t)2048 * 2048 * 4);
    _Float16* h1P    = (_Float16*)alloc((size_t)2304 * 1024 * 2 * 2);
    float*    h2buf  = (float*)alloc((size_t)2304 * 1024 * 4);
    _Float16* tanhP  = (_Float16*)alloc((size_t)2048 * 1024 * 2 * 2);

    const size_t NEm   = (size_t)2304 * 1024;
    const size_t NEt   = (size_t)2048 * 1024;
    const size_t NEbig = (size_t)8192 * 1024;

    size_t big_bytes = NEbig*2*2 + NEbig*4 + NEbig*2*2 + (size_t)8192*2048*4 + 8192;
    bool big = (ws_size >= off + big_bytes);

    dim3 tb(32, 8);
    k_transpose_split2<<<dim3(32, 32), tb, 0, stream>>>(W_in,  WinP,  WinP + NEin,  1024, 1024);
    k_transpose_split2<<<dim3(32, 96), tb, 0, stream>>>(W_qkv, WqkvP, WqkvP + NEqkv, 3072, 1024);
    k_transpose_split2<<<dim3(32, 32), tb, 0, stream>>>(W_mlp, WmlpP, WmlpP + NEmlp, 1024, 1024);
    k_transpose_split2<<<dim3(32, 64), tb, 0, stream>>>(W_ig,  WigP,  WigP + NEig,  2048, 1024);
    k_transpose_split2<<<dim3(32, 64), tb, 0, stream>>>(W_mg,  WmgP,  WmgP + NEmg,  2048, 1024);

    GemmP pq = { mbufP, mbufP + NEm, WqkvP, WqkvP + NEqkv, b_qkv, qkvbuf, 3072 };
    GemmP pg = { tanhP, tanhP + NEt, WmgP,  WmgP  + NEmg,  b_mg,  gmemb,  2048 };

    if (big) {
        _Float16* inputsP  = (_Float16*)alloc(NEbig * 2 * 2);
        float*    inp_all  = (float*)alloc(NEbig * 4);
        _Float16* inp_allP = (_Float16*)alloc(NEbig * 2 * 2);
        float*    ginp_all = (float*)alloc((size_t)8192 * 2048 * 4);

        k_split2_rows<<<8192, 256, 0, stream>>>(inputs, 1024, inputsP, inputsP + NEbig, 8192 * 256);
        k_gemm2<128,0,1,1><<<dim3(64, 8), 256, 0, stream>>>(inputsP, inputsP + NEbig,
            WinP, WinP + NEin, b_in, inp_all, 1024, inp_allP, inp_allP + NEbig);
        k_gemm2<128,0,1,0><<<dim3(64, 16), 256, 0, stream>>>(inp_allP, inp_allP + NEbig,
            WigP, WigP + NEig, b_ig, ginp_all, 2048, nullptr, nullptr);
        k_prep0<<<2304, 256, 0, stream>>>(mbuf, mbufP, mbufP + NEm, memory, mem_ws,
                                          tanhP, tanhP + NEt, inp_all, (long)SEQT * 1024);

        for (int t = 0; t < SEQT; t++) {
            k_gemm_pair<<<688, 256, 0, stream>>>(pq, 432, 18, pg, 16);
            k_ln_attn_addln1<<<BATCH, 512, 0, stream>>>(qkvbuf, g_qln, b_qln,
                mbuf, mbufP, mbufP + NEm, g_ln1, b_ln1);
            k_gemm2<64,1,0,1><<<dim3(36, 8), 256, 0, stream>>>(mbufP, mbufP + NEm,
                WmlpP, WmlpP + NEmlp, b_mlp, nullptr, 1024, h1P, h1P + NEm);
            k_gemm2<64,1,1,0><<<dim3(36, 8), 256, 0, stream>>>(h1P, h1P + NEm,
                WmlpP, WmlpP + NEmlp, b_mlp, h2buf, 1024, nullptr, nullptr);
            const float* inp_next = (t + 1 < SEQT) ? (inp_all + (size_t)(t + 1) * 1024) : nullptr;
            k_addln2_gate<<<BATCH, 512, 0, stream>>>(mbuf, h2buf, g_ln2, b_ln2,
                gmemb, ginp_all + (size_t)t * 2048, (long)SEQT * 2048,
                inp_next, (long)SEQT * 1024, fb, ib, mem_ws,
                out + (size_t)t * (BATCH * 8192),
                mbufP, mbufP + NEm, tanhP, tanhP + NEt);
        }
    } else {
        const size_t NEs = (size_t)256 * 1024;
        _Float16* stepP  = (_Float16*)alloc(NEs * 2 * 2);
        float*    inpA   = (float*)alloc(NEs * 4);
        _Float16* inpAP  = (_Float16*)alloc(NEs * 2 * 2);
        float*    inpB   = (float*)alloc(NEs * 4);
        _Float16* inpBP  = (_Float16*)alloc(NEs * 2 * 2);
        float*    ginpA  = (float*)alloc((size_t)256 * 2048 * 4);
        float*    ginpB  = (float*)alloc((size_t)256 * 2048 * 4);

        k_split2_rows<<<256, 256, 0, stream>>>(inputs, (long)SEQT * 1024, stepP, stepP + NEs, 256 * 256);
        k_gemm2<128,0,1,1><<<dim3(2, 8), 256, 0, stream>>>(stepP, stepP + NEs,
            WinP, WinP + NEin, b_in, inpA, 1024, inpAP, inpAP + NEs);
        k_gemm2<128,0,1,0><<<dim3(2, 16), 256, 0, stream>>>(inpAP, inpAP + NEs,
            WigP, WigP + NEig, b_ig, ginpA, 2048, nullptr, nullptr);
        k_prep0<<<2304, 256, 0, stream>>>(mbuf, mbufP, mbufP + NEm, memory, mem_ws,
                                          tanhP, tanhP + NEt, inpA, 1024);

        float *cg = ginpA, *ni = inpB, *ng = ginpB;
        _Float16* niP = inpBP;
        float* ci = inpA;
        _Float16* ciP = inpAP;
        for (int t = 0; t < SEQT; t++) {
            k_gemm_pair<<<688, 256, 0, stream>>>(pq, 432, 18, pg, 16);
            k_ln_attn_addln1<<<BATCH, 512, 0, stream>>>(qkvbuf, g_qln, b_qln,
                mbuf, mbufP, mbufP + NEm, g_ln1, b_ln1);
            k_gemm2<64,1,0,1><<<dim3(36, 8), 256, 0, stream>>>(mbufP, mbufP + NEm,
                WmlpP, WmlpP + NEmlp, b_mlp, nullptr, 1024, h1P, h1P + NEm);
            k_gemm2<64,1,1,0><<<dim3(36, 8), 256, 0, stream>>>(h1P, h1P + NEm,
                WmlpP, WmlpP + NEmlp, b_mlp, h2buf, 1024, nullptr, nullptr);
            const float* inp_next = nullptr;
            if (t + 1 < SEQT) {
                k_split2_rows<<<256, 256, 0, stream>>>(inputs + (size_t)(t + 1) * 1024,
                    (long)SEQT * 1024, stepP, stepP + NEs, 256 * 256);
                k_gemm2<128,0,1,1><<<dim3(2, 8), 256, 0, stream>>>(stepP, stepP + NEs,
                    WinP, WinP + NEin, b_in, ni, 1024, niP, niP + NEs);
                k_gemm2<128,0,1,0><<<dim3(2, 16), 256, 0, stream>>>(niP, niP + NEs,
                    WigP, WigP + NEig, b_ig, ng, 2048, nullptr, nullptr);
                inp_next = ni;
            }
            k_addln2_gate<<<BATCH, 512, 0, stream>>>(mbuf, h2buf, g_ln2, b_ln2,
                gmemb, cg, 2048, inp_next, 1024, fb, ib, mem_ws,
                out + (size_t)t * (BATCH * 8192),
                mbufP, mbufP + NEm, tanhP, tanhP + NEt);
            { float* tmp = ci; ci = ni; ni = tmp; }
            { float* tmp = cg; cg = ng; ng = tmp; }
            { _Float16* tmp = ciP; ciP = niP; niP = tmp; }
        }
    }
    k_copy<<<2048, 256, 0, stream>>>(mem_ws, out + (size_t)SEQT * BATCH * 8192, 524288);
}